// Round 8
// baseline (1870.725 us; speedup 1.0000x reference)
//
#include <hip/hip_runtime.h>
#include <cmath>

#define Bsz  4096
#define Tlen 512
#define Fnum 17
#define Hdim 32
#define Pnum 8
#define FPn  18
#define G3   96   // 3*Hdim
#define TPAD 8    // extra xT rows so the depth-4 prefetch ring never reads OOB

#define L2E   1.4426950408889634f
#define NL2E (-1.4426950408889634f)
#define TL2E  2.8853900817779268f   // 2*log2(e)

typedef __attribute__((ext_vector_type(8))) short short8v;
typedef __attribute__((ext_vector_type(4))) float float4v;
typedef __attribute__((ext_vector_type(2))) float float2v;

__device__ __forceinline__ float frcp(float x)  { return __builtin_amdgcn_rcpf(x); }
__device__ __forceinline__ float frsq(float x)  { return __builtin_amdgcn_rsqf(x); }
__device__ __forceinline__ float fexp2(float x) { return __builtin_amdgcn_exp2f(x); }
__device__ __forceinline__ float fsigmoid(float x) {
    return frcp(1.0f + fexp2(NL2E * x));
}
// compiler-packed f32 pair ops (backend may select v_pk_* for v2f32 — no inline asm)
__device__ __forceinline__ float2v fma2(float2v a, float2v b, float2v c) {
    return __builtin_elementwise_fma(a, b, c);
}
// RNE float->bf16 bits
__device__ __forceinline__ short bf16b(float x) {
    unsigned u = __float_as_uint(x);
    unsigned r = (u + 0x7FFFu + ((u >> 16) & 1u)) >> 16;
    return (short)r;
}
// packed f32x2 -> bf16x2 (hardware RNE) — proven since R2
__device__ __forceinline__ unsigned cvtpk(float lo, float hi) {
    unsigned r;
    asm("v_cvt_pk_bf16_f32 %0, %1, %2" : "=v"(r) : "v"(lo), "v"(hi));
    return r;
}

// ---------- prep: prototype L2 norms ----------
__global__ void prep_pnorm_kernel(const float* __restrict__ protos, float* __restrict__ pnorm) {
    const int p    = threadIdx.x >> 5;
    const int lane = threadIdx.x & 31;
    float s = 0.0f;
    for (int j = lane; j < FPn * Hdim; j += 32) {
        float v = protos[p * FPn * Hdim + j];
        s = fmaf(v, v, s);
    }
    #pragma unroll
    for (int m = 16; m; m >>= 1) s += __shfl_xor(s, m);
    if (lane == 0) pnorm[p] = sqrtf(s);
}

// ---------- prep: x[B,T,F] -> xT[F,T+TPAD,B] in bf16 ----------
__global__ __launch_bounds__(64)
void xpose_kernel(const float* __restrict__ x, unsigned short* __restrict__ xT) {
    const int b = blockIdx.x * 64 + threadIdx.x;
    const int t = blockIdx.y;
    const float* __restrict__ xp = x + ((size_t)b * Tlen + t) * Fnum;
    #pragma unroll
    for (int ff = 0; ff < Fnum; ++ff)
        xT[(size_t)ff * (Tlen + TPAD) * Bsz + (size_t)t * Bsz + b] = (unsigned short)bf16b(xp[ff]);
}

// ---------- main GRU via chained MFMA (R5-proven math) ------------------------
// Block = 4 waves; wave = (f, 16-b tile).
// Set1: a_m = Ws@h + C1  (C1 = fp32 bias: NL2E*(bih+bhh) for r,z; TL2E*bhh for n)
// Set2 (chained): e_m = Wx@[x] + a_m  for r,z; e_n = Wx@[x] + TL2E*bih_n for n.
// Row permutation (R2-validated): pi(m,rr) = (m>>1)*32 + 8*(rr>>2) + (m&1)*4 + (rr&3)
// => lane (c,S) tile m reg q holds gate unit j = 8S+(m&1)*4+q of b=B0+c — exactly
//    its own B-fragment slots for the next step.  r,z scaled by -log2e; n by 2log2e.
// Gate combine (R5 exact form): E=e^{2y}, ez=e^{-zhat}:
//   h' = [ez*(E-1) + h*(E+1)] / [(E+1)*(1+ez)]   (per-element rcp)
template<int USE_XT>
__global__ __launch_bounds__(256, 4)
void gru_mfma_kernel(const float* __restrict__ x,
                     const unsigned short* __restrict__ xT,
                     const float* __restrict__ Wih,   // [F,96]
                     const float* __restrict__ Whh,   // [F,96,32]
                     const float* __restrict__ bih,   // [F,96]
                     const float* __restrict__ bhh,   // [F,96]
                     float* __restrict__ pre)         // [B,18,32]
{
    const int f  = blockIdx.y;
    const int wv = threadIdx.x >> 6;
    const int l  = threadIdx.x & 63;
    const int B0 = blockIdx.x * 64 + wv * 16;
    const int c  = l & 15, S = l >> 4;
    const int b  = B0 + c;

    const float* __restrict__ whh_f = Whh + (size_t)f * G3 * Hdim;
    const float* __restrict__ wih_f = Wih + (size_t)f * G3;
    const float* __restrict__ bih_f = bih + (size_t)f * G3;
    const float* __restrict__ bhh_f = bhh + (size_t)f * G3;

    // ---- one-time per-lane constants ----
    short8v af0, af1, af2, af3, af4, af5;       // Whh fragments (set1)
    short8v g0, g1, g2, g3, g4, g5;             // Wih fragments (set2, k=0 col)
    float4v cin0, cin1, cin2, cin3, cin4, cin5; // fp32 set1 C (bias)
    float4v cb4, cb5;                           // fp32 set2 C for n tiles
    {
        union { short8v s; unsigned u[4]; } au, gu;
        #pragma unroll
        for (int m = 0; m < 6; ++m) {
            const int gate = m >> 1;
            const float sc = (gate < 2) ? NL2E : TL2E;
            const int gA = gate * 32 + 8 * (c >> 2) + (m & 1) * 4 + (c & 3);
            const float* wrow = whh_f + (size_t)gA * Hdim + 8 * S;
            #pragma unroll
            for (int u = 0; u < 4; ++u)
                au.u[u] = cvtpk(wrow[2 * u] * sc, wrow[2 * u + 1] * sc);
            gu.u[0] = (S == 0) ? cvtpk(sc * wih_f[gA], 0.0f) : 0u;
            gu.u[1] = 0u; gu.u[2] = 0u; gu.u[3] = 0u;
            float4v ci;
            #pragma unroll
            for (int q = 0; q < 4; ++q) {
                const int gC = gate * 32 + 8 * S + (m & 1) * 4 + q;
                ci[q] = (gate < 2) ? NL2E * (bhh_f[gC] + bih_f[gC])
                                   : TL2E * bhh_f[gC];
            }
            if (m == 0) { af0 = au.s; g0 = gu.s; cin0 = ci; }
            if (m == 1) { af1 = au.s; g1 = gu.s; cin1 = ci; }
            if (m == 2) { af2 = au.s; g2 = gu.s; cin2 = ci; }
            if (m == 3) { af3 = au.s; g3 = gu.s; cin3 = ci; }
            if (m == 4) { af4 = au.s; g4 = gu.s; cin4 = ci; }
            if (m == 5) { af5 = au.s; g5 = gu.s; cin5 = ci; }
        }
        #pragma unroll
        for (int q = 0; q < 4; ++q) {
            cb4[q] = TL2E * bih_f[64 + 8 * S + q];
            cb5[q] = TL2E * bih_f[64 + 8 * S + 4 + q];
        }
    }
    const unsigned msk = (S == 0) ? 0xFFFFu : 0u;   // only S=0 lanes feed k=0 of B2

    float2v h0 = {0,0}, h1 = {0,0}, h2 = {0,0}, h3 = {0,0};

    // B2 fragment: zero lanes hoisted out of the loop; u[0] written per step
    union { short8v s; unsigned u[4]; } b2;
    b2.u[0] = 0u; b2.u[1] = 0u; b2.u[2] = 0u; b2.u[3] = 0u;

    // ---- x prefetch ring, depth 4 (phase-relative offsets), raw bf16 bits ----
    const unsigned short* xtp = USE_XT ? (xT + (size_t)f * (Tlen + TPAD) * Bsz + b) : nullptr;
    const float* xp = USE_XT ? nullptr : (x + (size_t)b * Tlen * Fnum + f);
    unsigned x0, x1, x2, x3;
    if (USE_XT) {
        x0 = xtp[0 * Bsz]; x1 = xtp[1 * Bsz]; x2 = xtp[2 * Bsz]; x3 = xtp[3 * Bsz];
    } else {
        x0 = (unsigned short)bf16b(xp[0 * Fnum]);
        x1 = (unsigned short)bf16b(xp[1 * Fnum]);
        x2 = (unsigned short)bf16b(xp[2 * Fnum]);
        x3 = (unsigned short)bf16b(xp[3 * Fnum]);
    }

// ph is relative to the CURRENT xtp/xp (which corresponds to loop time t)
#define LOADX(ph) (USE_XT ? (unsigned)xtp[(size_t)(ph) * Bsz]                        \
                          : ((t + (ph) < Tlen) ? (unsigned)(unsigned short)bf16b(xp[(size_t)(ph) * Fnum]) : 0u))

// R5-proven gate combine, per packed pair (verbatim)
#define GATE_PAIR(hp, ar, az, an, en)                                           \
    {                                                                           \
        const float2v _ar = (ar), _az = (az), _an = (an), _en = (en);           \
        float2v er = {fexp2(_ar.x), fexp2(_ar.y)};                              \
        float2v rp = er + (float2v){1.0f, 1.0f};                                \
        float2v r  = {frcp(rp.x), frcp(rp.y)};                                  \
        float2v ez = {fexp2(_az.x), fexp2(_az.y)};                              \
        float2v y  = fma2(r, _an, _en);                                         \
        float2v E  = {fexp2(y.x), fexp2(y.y)};                                  \
        float2v num = fma2(ez, E, -ez) + fma2(hp, E, hp);                       \
        float2v den = (E + (float2v){1.0f, 1.0f}) * (ez + (float2v){1.0f, 1.0f});\
        float2v rd = {frcp(den.x), frcp(den.y)};                                \
        hp = num * rd;                                                          \
    }

#define LO2(v) ((float2v){(v)[0], (v)[1]})
#define HI2(v) ((float2v){(v)[2], (v)[3]})

#define GRU_STEP(xbits)                                                          \
    {                                                                            \
        union { short8v s; unsigned u[4]; } bu;                                  \
        bu.u[0] = cvtpk(h0.x, h0.y);                                             \
        bu.u[1] = cvtpk(h1.x, h1.y);                                             \
        bu.u[2] = cvtpk(h2.x, h2.y);                                             \
        bu.u[3] = cvtpk(h3.x, h3.y);                                             \
        b2.u[0] = (xbits) & msk;                                                 \
        __builtin_amdgcn_s_setprio(1);                                           \
        const float4v a0 = __builtin_amdgcn_mfma_f32_16x16x32_bf16(af0, bu.s, cin0, 0, 0, 0); \
        const float4v a1 = __builtin_amdgcn_mfma_f32_16x16x32_bf16(af1, bu.s, cin1, 0, 0, 0); \
        const float4v a2 = __builtin_amdgcn_mfma_f32_16x16x32_bf16(af2, bu.s, cin2, 0, 0, 0); \
        const float4v a3 = __builtin_amdgcn_mfma_f32_16x16x32_bf16(af3, bu.s, cin3, 0, 0, 0); \
        const float4v a4 = __builtin_amdgcn_mfma_f32_16x16x32_bf16(af4, bu.s, cin4, 0, 0, 0); \
        const float4v a5 = __builtin_amdgcn_mfma_f32_16x16x32_bf16(af5, bu.s, cin5, 0, 0, 0); \
        const float4v e0 = __builtin_amdgcn_mfma_f32_16x16x32_bf16(g0, b2.s, a0, 0, 0, 0); \
        const float4v e1 = __builtin_amdgcn_mfma_f32_16x16x32_bf16(g1, b2.s, a1, 0, 0, 0); \
        const float4v e2 = __builtin_amdgcn_mfma_f32_16x16x32_bf16(g2, b2.s, a2, 0, 0, 0); \
        const float4v e3 = __builtin_amdgcn_mfma_f32_16x16x32_bf16(g3, b2.s, a3, 0, 0, 0); \
        const float4v e4 = __builtin_amdgcn_mfma_f32_16x16x32_bf16(g4, b2.s, cb4, 0, 0, 0); \
        const float4v e5 = __builtin_amdgcn_mfma_f32_16x16x32_bf16(g5, b2.s, cb5, 0, 0, 0); \
        __builtin_amdgcn_s_setprio(0);                                           \
        GATE_PAIR(h0, LO2(e0), LO2(e2), LO2(a4), LO2(e4));                       \
        GATE_PAIR(h1, HI2(e0), HI2(e2), HI2(a4), HI2(e4));                       \
        GATE_PAIR(h2, LO2(e1), LO2(e3), LO2(a5), LO2(e5));                       \
        GATE_PAIR(h3, HI2(e1), HI2(e3), HI2(a5), HI2(e5));                       \
    }

    #pragma unroll 1
    for (int t = 0; t < Tlen; t += 4) {
        GRU_STEP(x0); x0 = LOADX(4);
        GRU_STEP(x1); x1 = LOADX(5);
        GRU_STEP(x2); x2 = LOADX(6);
        GRU_STEP(x3); x3 = LOADX(7);
        if (USE_XT) xtp += 4 * Bsz; else xp += 4 * Fnum;
    }

    float* __restrict__ o = pre + (size_t)b * (FPn * Hdim) + f * Hdim + 8 * S;
    o[0] = h0.x; o[1] = h0.y; o[2] = h1.x; o[3] = h1.y;
    o[4] = h2.x; o[5] = h2.y; o[6] = h3.x; o[7] = h3.y;
#undef GRU_STEP
#undef GATE_PAIR
#undef LOADX
#undef LO2
#undef HI2
}

// ---------- epilogue: 4 waves/block, 1 wave per b.  lane = (h = l&31, f-halfset = l>>5)
__global__ __launch_bounds__(256)
void post_kernel(const float* __restrict__ pre,     // [B,18,32] (f<17 valid)
                 const float* __restrict__ statics, // [B,4]
                 const float* __restrict__ demoW,   // [32,4]
                 const float* __restrict__ demob,   // [32]
                 const float* __restrict__ lnw,     // [18,32]
                 const float* __restrict__ lnb,     // [18,32]
                 const float* __restrict__ protos,  // [8,576]
                 const float* __restrict__ pnorm,   // [8]
                 const float* __restrict__ Wq,      // [32,8]
                 const float* __restrict__ bq,      // [32]
                 const float* __restrict__ Wk,      // [8,18]
                 const float* __restrict__ bk,      // [8]
                 const float* __restrict__ Wv,      // [8,18]
                 const float* __restrict__ bv,      // [8]
                 const float* __restrict__ outW,    // [32]
                 const float* __restrict__ outb,    // [1]
                 float* __restrict__ out_logits,    // [B]
                 float* __restrict__ out_dist,      // [B,8]
                 float* __restrict__ out_ht)        // [B,18,32]
{
    const int b     = blockIdx.x * 4 + (threadIdx.x >> 6);
    const int l     = threadIdx.x & 63;
    const int hl    = l & 31;
    const int fbase = (l >> 5) * 9;

    float v[9];
    #pragma unroll
    for (int j = 0; j < 9; ++j) {
        const int fj = fbase + j;
        if (fj == 17) {
            float acc = demob[hl];
            #pragma unroll
            for (int d = 0; d < 4; ++d)
                acc = fmaf(statics[b * 4 + d], demoW[hl * 4 + d], acc);
            v[j] = acc;
        } else {
            v[j] = pre[(size_t)b * 576 + fj * 32 + hl];
        }
    }

    float s = 0.0f, ss = 0.0f;
    #pragma unroll
    for (int j = 0; j < 9; ++j) { s += v[j]; ss = fmaf(v[j], v[j], ss); }
    #pragma unroll
    for (int m = 32; m; m >>= 1) { s += __shfl_xor(s, m); ss += __shfl_xor(ss, m); }
    const float mu  = s * (1.0f / 576.0f);
    const float var = ss * (1.0f / 576.0f) - mu * mu;
    const float rs  = frsq(var + 1e-5f);

    float nrm = 0.0f;
    #pragma unroll
    for (int j = 0; j < 9; ++j) {
        const int fj = fbase + j;
        float y = fmaf((v[j] - mu) * rs, lnw[fj * 32 + hl], lnb[fj * 32 + hl]);
        v[j] = y;
        out_ht[(size_t)b * 576 + fj * 32 + hl] = y;
        nrm = fmaf(y, y, nrm);
    }
    #pragma unroll
    for (int m = 32; m; m >>= 1) nrm += __shfl_xor(nrm, m);
    nrm = sqrtf(nrm);

    float dist[8];
    #pragma unroll
    for (int p = 0; p < Pnum; ++p) {
        float d = 0.0f;
        #pragma unroll
        for (int j = 0; j < 9; ++j)
            d = fmaf(v[j], protos[p * 576 + (fbase + j) * 32 + hl], d);
        #pragma unroll
        for (int m = 32; m; m >>= 1) d += __shfl_xor(d, m);
        dist[p] = d / fmaxf(nrm * pnorm[p], 1e-8f);
    }
    if (l == 0) {
        #pragma unroll
        for (int p = 0; p < Pnum; ++p) out_dist[(size_t)b * Pnum + p] = dist[p];
    }

    float q = bq[hl];
    #pragma unroll
    for (int p = 0; p < Pnum; ++p) q = fmaf(dist[p], Wq[hl * 8 + p], q);
    float Sq = q;
    #pragma unroll
    for (int m = 16; m; m >>= 1) Sq += __shfl_xor(Sq, m);

    float sf[9], so[9];
    #pragma unroll
    for (int j = 0; j < 9; ++j) {
        float t = v[j] * q;
        #pragma unroll
        for (int m = 16; m; m >>= 1) t += __shfl_xor(t, m);
        sf[j] = t;
    }
    #pragma unroll
    for (int j = 0; j < 9; ++j) so[j] = __shfl_xor(sf[j], 32);
    const int obase = 9 - fbase;

    float e[8];
    #pragma unroll
    for (int p = 0; p < Pnum; ++p) {
        float a = bk[p] * Sq;
        #pragma unroll
        for (int j = 0; j < 9; ++j) {
            a = fmaf(sf[j], Wk[p * FPn + fbase + j], a);
            a = fmaf(so[j], Wk[p * FPn + obase + j], a);
        }
        e[p] = a;
    }
    float mx = e[0];
    #pragma unroll
    for (int p = 1; p < Pnum; ++p) mx = fmaxf(mx, e[p]);
    float aw[8], den = 0.0f;
    #pragma unroll
    for (int p = 0; p < Pnum; ++p) { aw[p] = __expf(e[p] - mx); den += aw[p]; }
    const float rden = frcp(den);
    #pragma unroll
    for (int p = 0; p < Pnum; ++p) aw[p] *= rden;

    float cc = 0.0f;
    #pragma unroll
    for (int p = 0; p < Pnum; ++p) cc = fmaf(aw[p], bv[p], cc);
    float vb = 0.0f;
    #pragma unroll
    for (int j = 0; j < 9; ++j) {
        float wv = 0.0f;
        #pragma unroll
        for (int p = 0; p < Pnum; ++p) wv = fmaf(aw[p], Wv[p * FPn + fbase + j], wv);
        vb = fmaf(v[j], wv, vb);
    }
    vb += __shfl_xor(vb, 32);
    vb += cc;

    float lg = vb * outW[hl];
    #pragma unroll
    for (int m = 16; m; m >>= 1) lg += __shfl_xor(lg, m);
    lg = fsigmoid(lg + outb[0]);
    if (l == 0) out_logits[b] = lg;
}

extern "C" void kernel_launch(void* const* d_in, const int* in_sizes, int n_in,
                              void* d_out, int out_size, void* d_ws, size_t ws_size,
                              hipStream_t stream) {
    const float* x      = (const float*)d_in[0];
    const float* statics= (const float*)d_in[1];
    const float* Wih    = (const float*)d_in[2];
    const float* Whh    = (const float*)d_in[3];
    const float* bih    = (const float*)d_in[4];
    const float* bhh    = (const float*)d_in[5];
    const float* demoW  = (const float*)d_in[6];
    const float* demob  = (const float*)d_in[7];
    const float* lnw    = (const float*)d_in[8];
    const float* lnb    = (const float*)d_in[9];
    const float* protos = (const float*)d_in[10];
    const float* Wq     = (const float*)d_in[11];
    const float* bq     = (const float*)d_in[12];
    const float* Wk     = (const float*)d_in[13];
    const float* bk     = (const float*)d_in[14];
    const float* Wv     = (const float*)d_in[15];
    const float* bv     = (const float*)d_in[16];
    const float* outW   = (const float*)d_in[17];
    const float* outb   = (const float*)d_in[18];

    // ws layout: pre[B*576] f32 | pnorm[8] f32 | xT[F,T+TPAD,B] bf16
    float* pre   = (float*)d_ws;
    float* pnorm = pre + (size_t)Bsz * FPn * Hdim;
    unsigned short* xT = (unsigned short*)(pnorm + 8);
    const size_t need = ((size_t)Bsz * FPn * Hdim + 8) * 4
                      + (size_t)Fnum * (Tlen + TPAD) * Bsz * 2;
    const bool use_xt = (ws_size >= need);

    prep_pnorm_kernel<<<dim3(1), dim3(256), 0, stream>>>(protos, pnorm);

    if (use_xt) {
        xpose_kernel<<<dim3(Bsz / 64, Tlen), dim3(64), 0, stream>>>(x, xT);
        gru_mfma_kernel<1><<<dim3(Bsz / 64, Fnum), dim3(256), 0, stream>>>(
            x, xT, Wih, Whh, bih, bhh, pre);
    } else {
        gru_mfma_kernel<0><<<dim3(Bsz / 64, Fnum), dim3(256), 0, stream>>>(
            x, xT, Wih, Whh, bih, bhh, pre);
    }

    float* out_logits = (float*)d_out;
    float* out_dist   = out_logits + Bsz;
    float* out_ht     = out_dist + (size_t)Bsz * Pnum;

    post_kernel<<<dim3(Bsz / 4), dim3(256), 0, stream>>>(
        pre, statics, demoW, demob, lnw, lnb, protos, pnorm,
        Wq, bq, Wk, bk, Wv, bv, outW, outb,
        out_logits, out_dist, out_ht);
}

// Round 9
// 1084.104 us; speedup vs baseline: 1.7256x; 1.7256x over previous
//
#include <hip/hip_runtime.h>
#include <cmath>

#define Bsz  4096
#define Tlen 512
#define Fnum 17
#define Hdim 32
#define Pnum 8
#define FPn  18
#define G3   96   // 3*Hdim
#define TPAD 8    // extra xT rows so the depth-4 prefetch ring never reads OOB

#define L2E   1.4426950408889634f
#define NL2E (-1.4426950408889634f)
#define TL2E  2.8853900817779268f   // 2*log2(e)

typedef __attribute__((ext_vector_type(8))) short short8v;
typedef __attribute__((ext_vector_type(4))) float float4v;
typedef __attribute__((ext_vector_type(2))) float float2v;

__device__ __forceinline__ float frcp(float x)  { return __builtin_amdgcn_rcpf(x); }
__device__ __forceinline__ float frsq(float x)  { return __builtin_amdgcn_rsqf(x); }
__device__ __forceinline__ float fexp2(float x) { return __builtin_amdgcn_exp2f(x); }
__device__ __forceinline__ float fsigmoid(float x) {
    return frcp(1.0f + fexp2(NL2E * x));
}
// compiler-packed f32 pair ops (backend may select v_pk_* for v2f32 — no inline asm)
__device__ __forceinline__ float2v fma2(float2v a, float2v b, float2v c) {
    return __builtin_elementwise_fma(a, b, c);
}
// RNE float->bf16 bits
__device__ __forceinline__ short bf16b(float x) {
    unsigned u = __float_as_uint(x);
    unsigned r = (u + 0x7FFFu + ((u >> 16) & 1u)) >> 16;
    return (short)r;
}
// packed f32x2 -> bf16x2 (hardware RNE) — proven since R2
__device__ __forceinline__ unsigned cvtpk(float lo, float hi) {
    unsigned r;
    asm("v_cvt_pk_bf16_f32 %0, %1, %2" : "=v"(r) : "v"(lo), "v"(hi));
    return r;
}

// ---------- prep: prototype L2 norms ----------
__global__ void prep_pnorm_kernel(const float* __restrict__ protos, float* __restrict__ pnorm) {
    const int p    = threadIdx.x >> 5;
    const int lane = threadIdx.x & 31;
    float s = 0.0f;
    for (int j = lane; j < FPn * Hdim; j += 32) {
        float v = protos[p * FPn * Hdim + j];
        s = fmaf(v, v, s);
    }
    #pragma unroll
    for (int m = 16; m; m >>= 1) s += __shfl_xor(s, m);
    if (lane == 0) pnorm[p] = sqrtf(s);
}

// ---------- prep: x[B,T,F] -> xT[F,T+TPAD,B] in bf16 ----------
__global__ __launch_bounds__(64)
void xpose_kernel(const float* __restrict__ x, unsigned short* __restrict__ xT) {
    const int b = blockIdx.x * 64 + threadIdx.x;
    const int t = blockIdx.y;
    const float* __restrict__ xp = x + ((size_t)b * Tlen + t) * Fnum;
    #pragma unroll
    for (int ff = 0; ff < Fnum; ++ff)
        xT[(size_t)ff * (Tlen + TPAD) * Bsz + (size_t)t * Bsz + b] = (unsigned short)bf16b(xp[ff]);
}

// ---------- main GRU via chained MFMA (R5-proven math) ------------------------
// Block = 4 waves; wave = (f, 16-b tile).
// Set1: a_m = Ws@h + C1  (C1 = fp32 bias: NL2E*(bih+bhh) for r,z; TL2E*bhh for n)
// Set2 (chained): e_m = Wx@[x] + a_m  for r,z; e_n = Wx@[x] + TL2E*bih_n for n.
// Row permutation (R2-validated): pi(m,rr) = (m>>1)*32 + 8*(rr>>2) + (m&1)*4 + (rr&3)
// => lane (c,S) tile m reg q holds gate unit j = 8S+(m&1)*4+q of b=B0+c — exactly
//    its own B-fragment slots for the next step.  r,z scaled by -log2e; n by 2log2e.
// Gate combine (R5 exact form): E=e^{2y}, ez=e^{-zhat}:
//   h' = [ez*(E-1) + h*(E+1)] / [(E+1)*(1+ez)]   (per-element rcp)
// NOTE (R8 lesson): B-fragment unions MUST be declared and FULLY written inside
// the step — a hoisted, partially-updated union goes to scratch (3.3 GB FETCH).
template<int USE_XT>
__global__ __launch_bounds__(256, 4)
void gru_mfma_kernel(const float* __restrict__ x,
                     const unsigned short* __restrict__ xT,
                     const float* __restrict__ Wih,   // [F,96]
                     const float* __restrict__ Whh,   // [F,96,32]
                     const float* __restrict__ bih,   // [F,96]
                     const float* __restrict__ bhh,   // [F,96]
                     float* __restrict__ pre)         // [B,18,32]
{
    const int f  = blockIdx.y;
    const int wv = threadIdx.x >> 6;
    const int l  = threadIdx.x & 63;
    const int B0 = blockIdx.x * 64 + wv * 16;
    const int c  = l & 15, S = l >> 4;
    const int b  = B0 + c;

    const float* __restrict__ whh_f = Whh + (size_t)f * G3 * Hdim;
    const float* __restrict__ wih_f = Wih + (size_t)f * G3;
    const float* __restrict__ bih_f = bih + (size_t)f * G3;
    const float* __restrict__ bhh_f = bhh + (size_t)f * G3;

    // ---- one-time per-lane constants ----
    short8v af0, af1, af2, af3, af4, af5;       // Whh fragments (set1)
    short8v g0, g1, g2, g3, g4, g5;             // Wih fragments (set2, k=0 col)
    float4v cin0, cin1, cin2, cin3, cin4, cin5; // fp32 set1 C (bias)
    float4v cb4, cb5;                           // fp32 set2 C for n tiles
    {
        union { short8v s; unsigned u[4]; } au, gu;
        #pragma unroll
        for (int m = 0; m < 6; ++m) {
            const int gate = m >> 1;
            const float sc = (gate < 2) ? NL2E : TL2E;
            const int gA = gate * 32 + 8 * (c >> 2) + (m & 1) * 4 + (c & 3);
            const float* wrow = whh_f + (size_t)gA * Hdim + 8 * S;
            #pragma unroll
            for (int u = 0; u < 4; ++u)
                au.u[u] = cvtpk(wrow[2 * u] * sc, wrow[2 * u + 1] * sc);
            gu.u[0] = (S == 0) ? cvtpk(sc * wih_f[gA], 0.0f) : 0u;
            gu.u[1] = 0u; gu.u[2] = 0u; gu.u[3] = 0u;
            float4v ci;
            #pragma unroll
            for (int q = 0; q < 4; ++q) {
                const int gC = gate * 32 + 8 * S + (m & 1) * 4 + q;
                ci[q] = (gate < 2) ? NL2E * (bhh_f[gC] + bih_f[gC])
                                   : TL2E * bhh_f[gC];
            }
            if (m == 0) { af0 = au.s; g0 = gu.s; cin0 = ci; }
            if (m == 1) { af1 = au.s; g1 = gu.s; cin1 = ci; }
            if (m == 2) { af2 = au.s; g2 = gu.s; cin2 = ci; }
            if (m == 3) { af3 = au.s; g3 = gu.s; cin3 = ci; }
            if (m == 4) { af4 = au.s; g4 = gu.s; cin4 = ci; }
            if (m == 5) { af5 = au.s; g5 = gu.s; cin5 = ci; }
        }
        #pragma unroll
        for (int q = 0; q < 4; ++q) {
            cb4[q] = TL2E * bih_f[64 + 8 * S + q];
            cb5[q] = TL2E * bih_f[64 + 8 * S + 4 + q];
        }
    }
    const unsigned msk = (S == 0) ? 0xFFFFu : 0u;   // only S=0 lanes feed k=0 of B2

    float2v h0 = {0,0}, h1 = {0,0}, h2 = {0,0}, h3 = {0,0};

    // ---- x prefetch ring, depth 4 (phase-relative offsets), raw bf16 bits ----
    const unsigned short* xtp = USE_XT ? (xT + (size_t)f * (Tlen + TPAD) * Bsz + b) : nullptr;
    const float* xp = USE_XT ? nullptr : (x + (size_t)b * Tlen * Fnum + f);
    unsigned x0, x1, x2, x3;
    if (USE_XT) {
        x0 = xtp[0 * Bsz]; x1 = xtp[1 * Bsz]; x2 = xtp[2 * Bsz]; x3 = xtp[3 * Bsz];
    } else {
        x0 = (unsigned short)bf16b(xp[0 * Fnum]);
        x1 = (unsigned short)bf16b(xp[1 * Fnum]);
        x2 = (unsigned short)bf16b(xp[2 * Fnum]);
        x3 = (unsigned short)bf16b(xp[3 * Fnum]);
    }

// ph is relative to the CURRENT xtp/xp (which corresponds to loop time t)
#define LOADX(ph) (USE_XT ? (unsigned)xtp[(size_t)(ph) * Bsz]                        \
                          : ((t + (ph) < Tlen) ? (unsigned)(unsigned short)bf16b(xp[(size_t)(ph) * Fnum]) : 0u))

// R5-proven gate combine, per packed pair (verbatim)
#define GATE_PAIR(hp, ar, az, an, en)                                           \
    {                                                                           \
        const float2v _ar = (ar), _az = (az), _an = (an), _en = (en);           \
        float2v er = {fexp2(_ar.x), fexp2(_ar.y)};                              \
        float2v rp = er + (float2v){1.0f, 1.0f};                                \
        float2v r  = {frcp(rp.x), frcp(rp.y)};                                  \
        float2v ez = {fexp2(_az.x), fexp2(_az.y)};                              \
        float2v y  = fma2(r, _an, _en);                                         \
        float2v E  = {fexp2(y.x), fexp2(y.y)};                                  \
        float2v num = fma2(ez, E, -ez) + fma2(hp, E, hp);                       \
        float2v den = (E + (float2v){1.0f, 1.0f}) * (ez + (float2v){1.0f, 1.0f});\
        float2v rd = {frcp(den.x), frcp(den.y)};                                \
        hp = num * rd;                                                          \
    }

#define LO2(v) ((float2v){(v)[0], (v)[1]})
#define HI2(v) ((float2v){(v)[2], (v)[3]})

#define GRU_STEP(xbits)                                                          \
    {                                                                            \
        union { short8v s; unsigned u[4]; } bu;                                  \
        bu.u[0] = cvtpk(h0.x, h0.y);                                             \
        bu.u[1] = cvtpk(h1.x, h1.y);                                             \
        bu.u[2] = cvtpk(h2.x, h2.y);                                             \
        bu.u[3] = cvtpk(h3.x, h3.y);                                             \
        union { short8v s; unsigned u[4]; } b2;                                  \
        b2.u[0] = (xbits) & msk;                                                 \
        b2.u[1] = 0u; b2.u[2] = 0u; b2.u[3] = 0u;                                \
        __builtin_amdgcn_s_setprio(1);                                           \
        const float4v a0 = __builtin_amdgcn_mfma_f32_16x16x32_bf16(af0, bu.s, cin0, 0, 0, 0); \
        const float4v a1 = __builtin_amdgcn_mfma_f32_16x16x32_bf16(af1, bu.s, cin1, 0, 0, 0); \
        const float4v a2 = __builtin_amdgcn_mfma_f32_16x16x32_bf16(af2, bu.s, cin2, 0, 0, 0); \
        const float4v a3 = __builtin_amdgcn_mfma_f32_16x16x32_bf16(af3, bu.s, cin3, 0, 0, 0); \
        const float4v a4 = __builtin_amdgcn_mfma_f32_16x16x32_bf16(af4, bu.s, cin4, 0, 0, 0); \
        const float4v a5 = __builtin_amdgcn_mfma_f32_16x16x32_bf16(af5, bu.s, cin5, 0, 0, 0); \
        const float4v e0 = __builtin_amdgcn_mfma_f32_16x16x32_bf16(g0, b2.s, a0, 0, 0, 0); \
        const float4v e1 = __builtin_amdgcn_mfma_f32_16x16x32_bf16(g1, b2.s, a1, 0, 0, 0); \
        const float4v e2 = __builtin_amdgcn_mfma_f32_16x16x32_bf16(g2, b2.s, a2, 0, 0, 0); \
        const float4v e3 = __builtin_amdgcn_mfma_f32_16x16x32_bf16(g3, b2.s, a3, 0, 0, 0); \
        const float4v e4 = __builtin_amdgcn_mfma_f32_16x16x32_bf16(g4, b2.s, cb4, 0, 0, 0); \
        const float4v e5 = __builtin_amdgcn_mfma_f32_16x16x32_bf16(g5, b2.s, cb5, 0, 0, 0); \
        __builtin_amdgcn_s_setprio(0);                                           \
        GATE_PAIR(h0, LO2(e0), LO2(e2), LO2(a4), LO2(e4));                       \
        GATE_PAIR(h1, HI2(e0), HI2(e2), HI2(a4), HI2(e4));                       \
        GATE_PAIR(h2, LO2(e1), LO2(e3), LO2(a5), LO2(e5));                       \
        GATE_PAIR(h3, HI2(e1), HI2(e3), HI2(a5), HI2(e5));                       \
    }

    #pragma unroll 1
    for (int t = 0; t < Tlen; t += 4) {
        GRU_STEP(x0); x0 = LOADX(4);
        GRU_STEP(x1); x1 = LOADX(5);
        GRU_STEP(x2); x2 = LOADX(6);
        GRU_STEP(x3); x3 = LOADX(7);
        if (USE_XT) xtp += 4 * Bsz; else xp += 4 * Fnum;
    }

    float* __restrict__ o = pre + (size_t)b * (FPn * Hdim) + f * Hdim + 8 * S;
    o[0] = h0.x; o[1] = h0.y; o[2] = h1.x; o[3] = h1.y;
    o[4] = h2.x; o[5] = h2.y; o[6] = h3.x; o[7] = h3.y;
#undef GRU_STEP
#undef GATE_PAIR
#undef LOADX
#undef LO2
#undef HI2
}

// ---------- epilogue: 4 waves/block, 1 wave per b.  lane = (h = l&31, f-halfset = l>>5)
__global__ __launch_bounds__(256)
void post_kernel(const float* __restrict__ pre,     // [B,18,32] (f<17 valid)
                 const float* __restrict__ statics, // [B,4]
                 const float* __restrict__ demoW,   // [32,4]
                 const float* __restrict__ demob,   // [32]
                 const float* __restrict__ lnw,     // [18,32]
                 const float* __restrict__ lnb,     // [18,32]
                 const float* __restrict__ protos,  // [8,576]
                 const float* __restrict__ pnorm,   // [8]
                 const float* __restrict__ Wq,      // [32,8]
                 const float* __restrict__ bq,      // [32]
                 const float* __restrict__ Wk,      // [8,18]
                 const float* __restrict__ bk,      // [8]
                 const float* __restrict__ Wv,      // [8,18]
                 const float* __restrict__ bv,      // [8]
                 const float* __restrict__ outW,    // [32]
                 const float* __restrict__ outb,    // [1]
                 float* __restrict__ out_logits,    // [B]
                 float* __restrict__ out_dist,      // [B,8]
                 float* __restrict__ out_ht)        // [B,18,32]
{
    const int b     = blockIdx.x * 4 + (threadIdx.x >> 6);
    const int l     = threadIdx.x & 63;
    const int hl    = l & 31;
    const int fbase = (l >> 5) * 9;

    float v[9];
    #pragma unroll
    for (int j = 0; j < 9; ++j) {
        const int fj = fbase + j;
        if (fj == 17) {
            float acc = demob[hl];
            #pragma unroll
            for (int d = 0; d < 4; ++d)
                acc = fmaf(statics[b * 4 + d], demoW[hl * 4 + d], acc);
            v[j] = acc;
        } else {
            v[j] = pre[(size_t)b * 576 + fj * 32 + hl];
        }
    }

    float s = 0.0f, ss = 0.0f;
    #pragma unroll
    for (int j = 0; j < 9; ++j) { s += v[j]; ss = fmaf(v[j], v[j], ss); }
    #pragma unroll
    for (int m = 32; m; m >>= 1) { s += __shfl_xor(s, m); ss += __shfl_xor(ss, m); }
    const float mu  = s * (1.0f / 576.0f);
    const float var = ss * (1.0f / 576.0f) - mu * mu;
    const float rs  = frsq(var + 1e-5f);

    float nrm = 0.0f;
    #pragma unroll
    for (int j = 0; j < 9; ++j) {
        const int fj = fbase + j;
        float y = fmaf((v[j] - mu) * rs, lnw[fj * 32 + hl], lnb[fj * 32 + hl]);
        v[j] = y;
        out_ht[(size_t)b * 576 + fj * 32 + hl] = y;
        nrm = fmaf(y, y, nrm);
    }
    #pragma unroll
    for (int m = 32; m; m >>= 1) nrm += __shfl_xor(nrm, m);
    nrm = sqrtf(nrm);

    float dist[8];
    #pragma unroll
    for (int p = 0; p < Pnum; ++p) {
        float d = 0.0f;
        #pragma unroll
        for (int j = 0; j < 9; ++j)
            d = fmaf(v[j], protos[p * 576 + (fbase + j) * 32 + hl], d);
        #pragma unroll
        for (int m = 32; m; m >>= 1) d += __shfl_xor(d, m);
        dist[p] = d / fmaxf(nrm * pnorm[p], 1e-8f);
    }
    if (l == 0) {
        #pragma unroll
        for (int p = 0; p < Pnum; ++p) out_dist[(size_t)b * Pnum + p] = dist[p];
    }

    float q = bq[hl];
    #pragma unroll
    for (int p = 0; p < Pnum; ++p) q = fmaf(dist[p], Wq[hl * 8 + p], q);
    float Sq = q;
    #pragma unroll
    for (int m = 16; m; m >>= 1) Sq += __shfl_xor(Sq, m);

    float sf[9], so[9];
    #pragma unroll
    for (int j = 0; j < 9; ++j) {
        float t = v[j] * q;
        #pragma unroll
        for (int m = 16; m; m >>= 1) t += __shfl_xor(t, m);
        sf[j] = t;
    }
    #pragma unroll
    for (int j = 0; j < 9; ++j) so[j] = __shfl_xor(sf[j], 32);
    const int obase = 9 - fbase;

    float e[8];
    #pragma unroll
    for (int p = 0; p < Pnum; ++p) {
        float a = bk[p] * Sq;
        #pragma unroll
        for (int j = 0; j < 9; ++j) {
            a = fmaf(sf[j], Wk[p * FPn + fbase + j], a);
            a = fmaf(so[j], Wk[p * FPn + obase + j], a);
        }
        e[p] = a;
    }
    float mx = e[0];
    #pragma unroll
    for (int p = 1; p < Pnum; ++p) mx = fmaxf(mx, e[p]);
    float aw[8], den = 0.0f;
    #pragma unroll
    for (int p = 0; p < Pnum; ++p) { aw[p] = __expf(e[p] - mx); den += aw[p]; }
    const float rden = frcp(den);
    #pragma unroll
    for (int p = 0; p < Pnum; ++p) aw[p] *= rden;

    float cc = 0.0f;
    #pragma unroll
    for (int p = 0; p < Pnum; ++p) cc = fmaf(aw[p], bv[p], cc);
    float vb = 0.0f;
    #pragma unroll
    for (int j = 0; j < 9; ++j) {
        float wv = 0.0f;
        #pragma unroll
        for (int p = 0; p < Pnum; ++p) wv = fmaf(aw[p], Wv[p * FPn + fbase + j], wv);
        vb = fmaf(v[j], wv, vb);
    }
    vb += __shfl_xor(vb, 32);
    vb += cc;

    float lg = vb * outW[hl];
    #pragma unroll
    for (int m = 16; m; m >>= 1) lg += __shfl_xor(lg, m);
    lg = fsigmoid(lg + outb[0]);
    if (l == 0) out_logits[b] = lg;
}

extern "C" void kernel_launch(void* const* d_in, const int* in_sizes, int n_in,
                              void* d_out, int out_size, void* d_ws, size_t ws_size,
                              hipStream_t stream) {
    const float* x      = (const float*)d_in[0];
    const float* statics= (const float*)d_in[1];
    const float* Wih    = (const float*)d_in[2];
    const float* Whh    = (const float*)d_in[3];
    const float* bih    = (const float*)d_in[4];
    const float* bhh    = (const float*)d_in[5];
    const float* demoW  = (const float*)d_in[6];
    const float* demob  = (const float*)d_in[7];
    const float* lnw    = (const float*)d_in[8];
    const float* lnb    = (const float*)d_in[9];
    const float* protos = (const float*)d_in[10];
    const float* Wq     = (const float*)d_in[11];
    const float* bq     = (const float*)d_in[12];
    const float* Wk     = (const float*)d_in[13];
    const float* bk     = (const float*)d_in[14];
    const float* Wv     = (const float*)d_in[15];
    const float* bv     = (const float*)d_in[16];
    const float* outW   = (const float*)d_in[17];
    const float* outb   = (const float*)d_in[18];

    // ws layout: pre[B*576] f32 | pnorm[8] f32 | xT[F,T+TPAD,B] bf16
    float* pre   = (float*)d_ws;
    float* pnorm = pre + (size_t)Bsz * FPn * Hdim;
    unsigned short* xT = (unsigned short*)(pnorm + 8);
    const size_t need = ((size_t)Bsz * FPn * Hdim + 8) * 4
                      + (size_t)Fnum * (Tlen + TPAD) * Bsz * 2;
    const bool use_xt = (ws_size >= need);

    prep_pnorm_kernel<<<dim3(1), dim3(256), 0, stream>>>(protos, pnorm);

    if (use_xt) {
        xpose_kernel<<<dim3(Bsz / 64, Tlen), dim3(64), 0, stream>>>(x, xT);
        gru_mfma_kernel<1><<<dim3(Bsz / 64, Fnum), dim3(256), 0, stream>>>(
            x, xT, Wih, Whh, bih, bhh, pre);
    } else {
        gru_mfma_kernel<0><<<dim3(Bsz / 64, Fnum), dim3(256), 0, stream>>>(
            x, xT, Wih, Whh, bih, bhh, pre);
    }

    float* out_logits = (float*)d_out;
    float* out_dist   = out_logits + Bsz;
    float* out_ht     = out_dist + (size_t)Bsz * Pnum;

    post_kernel<<<dim3(Bsz / 4), dim3(256), 0, stream>>>(
        pre, statics, demoW, demob, lnw, lnb, protos, pnorm,
        Wq, bq, Wk, bk, Wv, bv, outW, outb,
        out_logits, out_dist, out_ht);
}

// Round 11
// 996.922 us; speedup vs baseline: 1.8765x; 1.0875x over previous
//
#include <hip/hip_runtime.h>
#include <cmath>

#define Bsz  4096
#define Tlen 512
#define Fnum 17
#define Hdim 32
#define Pnum 8
#define FPn  18
#define G3   96   // 3*Hdim
#define TPAD 8    // extra xT rows so the depth-4 prefetch ring never reads OOB

#define L2E   1.4426950408889634f
#define NL2E (-1.4426950408889634f)
#define TL2E  2.8853900817779268f   // 2*log2(e)

typedef __attribute__((ext_vector_type(8))) short short8v;
typedef __attribute__((ext_vector_type(4))) float float4v;
typedef __attribute__((ext_vector_type(2))) float float2v;
typedef __attribute__((ext_vector_type(4))) unsigned uint4v;

__device__ __forceinline__ float frcp(float x)  { return __builtin_amdgcn_rcpf(x); }
__device__ __forceinline__ float frsq(float x)  { return __builtin_amdgcn_rsqf(x); }
__device__ __forceinline__ float fexp2(float x) { return __builtin_amdgcn_exp2f(x); }
__device__ __forceinline__ float fsigmoid(float x) {
    return frcp(1.0f + fexp2(NL2E * x));
}
__device__ __forceinline__ float2v fma2(float2v a, float2v b, float2v c) {
    return __builtin_elementwise_fma(a, b, c);
}
// well-defined fragment assembly (no union type-punning — R10 lesson)
__device__ __forceinline__ short8v mk8(unsigned a, unsigned b, unsigned c, unsigned d) {
    uint4v v = {a, b, c, d};
    return __builtin_bit_cast(short8v, v);
}
// RNE float->bf16 bits
__device__ __forceinline__ short bf16b(float x) {
    unsigned u = __float_as_uint(x);
    unsigned r = (u + 0x7FFFu + ((u >> 16) & 1u)) >> 16;
    return (short)r;
}
// packed f32x2 -> bf16x2 (hardware RNE) — proven since R2
__device__ __forceinline__ unsigned cvtpk(float lo, float hi) {
    unsigned r;
    asm("v_cvt_pk_bf16_f32 %0, %1, %2" : "=v"(r) : "v"(lo), "v"(hi));
    return r;
}

// ---------- prep: prototype L2 norms ----------
__global__ void prep_pnorm_kernel(const float* __restrict__ protos, float* __restrict__ pnorm) {
    const int p    = threadIdx.x >> 5;
    const int lane = threadIdx.x & 31;
    float s = 0.0f;
    for (int j = lane; j < FPn * Hdim; j += 32) {
        float v = protos[p * FPn * Hdim + j];
        s = fmaf(v, v, s);
    }
    #pragma unroll
    for (int m = 16; m; m >>= 1) s += __shfl_xor(s, m);
    if (lane == 0) pnorm[p] = sqrtf(s);
}

// ---------- prep: x[B,T,F] -> xT[F,T+TPAD,B] in bf16 ----------
__global__ __launch_bounds__(64)
void xpose_kernel(const float* __restrict__ x, unsigned short* __restrict__ xT) {
    const int b = blockIdx.x * 64 + threadIdx.x;
    const int t = blockIdx.y;
    const float* __restrict__ xp = x + ((size_t)b * Tlen + t) * Fnum;
    #pragma unroll
    for (int ff = 0; ff < Fnum; ++ff)
        xT[(size_t)ff * (Tlen + TPAD) * Bsz + (size_t)t * Bsz + b] = (unsigned short)bf16b(xp[ff]);
}

// ---------- main GRU via chained MFMA (R5-proven math), 2 tiles per wave ------
// Block = 4 waves; wave = (f, TWO independent 16-b tiles A/B at B0 and B0+16).
// Weight fragments (af,g,cin,cb) are b-independent => shared; 2nd chain costs
// only h(8)+ring(4) VGPRs and fills the 1st chain's latency bubbles.
// Set1: a_m = Ws@h + C1; Set2 chained: e_m = Wx@[x] + a_m (r,z), e_n = Wx@[x]+C2.
// pi(m,rr) = (m>>1)*32 + 8*(rr>>2) + (m&1)*4 + (rr&3)  [R2-validated]
// Gate combine (R5 exact): E=e^{2y}, ez=e^{-zhat}:
//   h' = [ez*(E-1) + h*(E+1)] / [(E+1)*(1+ez)]
// Codegen rules learned: fragments assembled via bit_cast (NO unions, R10),
// declared+built inside the step (R8), NO setprio in reg-tight loop (R9).
template<int USE_XT>
__global__ __launch_bounds__(256, 2)
void gru_mfma_kernel(const float* __restrict__ x,
                     const unsigned short* __restrict__ xT,
                     const float* __restrict__ Wih,   // [F,96]
                     const float* __restrict__ Whh,   // [F,96,32]
                     const float* __restrict__ bih,   // [F,96]
                     const float* __restrict__ bhh,   // [F,96]
                     float* __restrict__ pre)         // [B,18,32]
{
    const int f  = blockIdx.y;
    const int wv = threadIdx.x >> 6;
    const int l  = threadIdx.x & 63;
    const int c  = l & 15, S = l >> 4;
    const int ba = blockIdx.x * 128 + wv * 32 + c;   // tile A lane's b
    const int bb = ba + 16;                          // tile B lane's b

    const float* __restrict__ whh_f = Whh + (size_t)f * G3 * Hdim;
    const float* __restrict__ wih_f = Wih + (size_t)f * G3;
    const float* __restrict__ bih_f = bih + (size_t)f * G3;
    const float* __restrict__ bhh_f = bhh + (size_t)f * G3;

    // ---- one-time per-lane constants (shared by both tiles) ----
    short8v af0, af1, af2, af3, af4, af5;       // Whh fragments (set1)
    short8v g0, g1, g2, g3, g4, g5;             // Wih fragments (set2, k=0 col)
    float4v cin0, cin1, cin2, cin3, cin4, cin5; // fp32 set1 C (bias)
    float4v cb4, cb5;                           // fp32 set2 C for n tiles
    {
        #pragma unroll
        for (int m = 0; m < 6; ++m) {
            const int gate = m >> 1;
            const float sc = (gate < 2) ? NL2E : TL2E;
            const int gA = gate * 32 + 8 * (c >> 2) + (m & 1) * 4 + (c & 3);
            const float* wrow = whh_f + (size_t)gA * Hdim + 8 * S;
            short8v af = mk8(cvtpk(wrow[0] * sc, wrow[1] * sc),
                             cvtpk(wrow[2] * sc, wrow[3] * sc),
                             cvtpk(wrow[4] * sc, wrow[5] * sc),
                             cvtpk(wrow[6] * sc, wrow[7] * sc));
            short8v gg = mk8((S == 0) ? cvtpk(sc * wih_f[gA], 0.0f) : 0u, 0u, 0u, 0u);
            float4v ci;
            #pragma unroll
            for (int q = 0; q < 4; ++q) {
                const int gC = gate * 32 + 8 * S + (m & 1) * 4 + q;
                ci[q] = (gate < 2) ? NL2E * (bhh_f[gC] + bih_f[gC])
                                   : TL2E * bhh_f[gC];
            }
            if (m == 0) { af0 = af; g0 = gg; cin0 = ci; }
            if (m == 1) { af1 = af; g1 = gg; cin1 = ci; }
            if (m == 2) { af2 = af; g2 = gg; cin2 = ci; }
            if (m == 3) { af3 = af; g3 = gg; cin3 = ci; }
            if (m == 4) { af4 = af; g4 = gg; cin4 = ci; }
            if (m == 5) { af5 = af; g5 = gg; cin5 = ci; }
        }
        #pragma unroll
        for (int q = 0; q < 4; ++q) {
            cb4[q] = TL2E * bih_f[64 + 8 * S + q];
            cb5[q] = TL2E * bih_f[64 + 8 * S + 4 + q];
        }
    }
    const unsigned msk = (S == 0) ? 0xFFFFu : 0u;   // only S=0 lanes feed k=0 of B2

    float2v h0a = {0,0}, h1a = {0,0}, h2a = {0,0}, h3a = {0,0};
    float2v h0b = {0,0}, h1b = {0,0}, h2b = {0,0}, h3b = {0,0};

    // ---- x prefetch rings, depth 4 per tile (phase-relative), raw bf16 bits ----
    const unsigned short* xta = USE_XT ? (xT + (size_t)f * (Tlen + TPAD) * Bsz + ba) : nullptr;
    const unsigned short* xtb = USE_XT ? (xT + (size_t)f * (Tlen + TPAD) * Bsz + bb) : nullptr;
    const float* xpa = USE_XT ? nullptr : (x + (size_t)ba * Tlen * Fnum + f);
    const float* xpb = USE_XT ? nullptr : (x + (size_t)bb * Tlen * Fnum + f);
    unsigned x0a, x1a, x2a, x3a, x0b, x1b, x2b, x3b;
    if (USE_XT) {
        x0a = xta[0 * Bsz]; x1a = xta[1 * Bsz]; x2a = xta[2 * Bsz]; x3a = xta[3 * Bsz];
        x0b = xtb[0 * Bsz]; x1b = xtb[1 * Bsz]; x2b = xtb[2 * Bsz]; x3b = xtb[3 * Bsz];
    } else {
        x0a = (unsigned short)bf16b(xpa[0 * Fnum]); x1a = (unsigned short)bf16b(xpa[1 * Fnum]);
        x2a = (unsigned short)bf16b(xpa[2 * Fnum]); x3a = (unsigned short)bf16b(xpa[3 * Fnum]);
        x0b = (unsigned short)bf16b(xpb[0 * Fnum]); x1b = (unsigned short)bf16b(xpb[1 * Fnum]);
        x2b = (unsigned short)bf16b(xpb[2 * Fnum]); x3b = (unsigned short)bf16b(xpb[3 * Fnum]);
    }

// ph is relative to the CURRENT pointers (which correspond to loop time t)
#define LOADXA(ph) (USE_XT ? (unsigned)xta[(size_t)(ph) * Bsz]                      \
                           : ((t + (ph) < Tlen) ? (unsigned)(unsigned short)bf16b(xpa[(size_t)(ph) * Fnum]) : 0u))
#define LOADXB(ph) (USE_XT ? (unsigned)xtb[(size_t)(ph) * Bsz]                      \
                           : ((t + (ph) < Tlen) ? (unsigned)(unsigned short)bf16b(xpb[(size_t)(ph) * Fnum]) : 0u))

// R5-proven gate combine, per packed pair (verbatim)
#define GATE_PAIR(hp, ar, az, an, en)                                           \
    {                                                                           \
        const float2v _ar = (ar), _az = (az), _an = (an), _en = (en);           \
        float2v er = {fexp2(_ar.x), fexp2(_ar.y)};                              \
        float2v rp = er + (float2v){1.0f, 1.0f};                                \
        float2v r  = {frcp(rp.x), frcp(rp.y)};                                  \
        float2v ez = {fexp2(_az.x), fexp2(_az.y)};                              \
        float2v y  = fma2(r, _an, _en);                                         \
        float2v E  = {fexp2(y.x), fexp2(y.y)};                                  \
        float2v num = fma2(ez, E, -ez) + fma2(hp, E, hp);                       \
        float2v den = (E + (float2v){1.0f, 1.0f}) * (ez + (float2v){1.0f, 1.0f});\
        float2v rd = {frcp(den.x), frcp(den.y)};                                \
        hp = num * rd;                                                          \
    }

#define LO2(v) ((float2v){(v)[0], (v)[1]})
#define HI2(v) ((float2v){(v)[2], (v)[3]})

// one timestep for BOTH tiles; independent chains interleave in the scheduler
#define GRU_STEP2(xba, xbb)                                                      \
    {                                                                            \
        const short8v buA = mk8(cvtpk(h0a.x, h0a.y), cvtpk(h1a.x, h1a.y),        \
                                cvtpk(h2a.x, h2a.y), cvtpk(h3a.x, h3a.y));       \
        const short8v buB = mk8(cvtpk(h0b.x, h0b.y), cvtpk(h1b.x, h1b.y),        \
                                cvtpk(h2b.x, h2b.y), cvtpk(h3b.x, h3b.y));       \
        const short8v b2A = mk8((xba) & msk, 0u, 0u, 0u);                        \
        const short8v b2B = mk8((xbb) & msk, 0u, 0u, 0u);                        \
        const float4v a0A = __builtin_amdgcn_mfma_f32_16x16x32_bf16(af0, buA, cin0, 0, 0, 0); \
        const float4v a1A = __builtin_amdgcn_mfma_f32_16x16x32_bf16(af1, buA, cin1, 0, 0, 0); \
        const float4v a2A = __builtin_amdgcn_mfma_f32_16x16x32_bf16(af2, buA, cin2, 0, 0, 0); \
        const float4v a3A = __builtin_amdgcn_mfma_f32_16x16x32_bf16(af3, buA, cin3, 0, 0, 0); \
        const float4v a4A = __builtin_amdgcn_mfma_f32_16x16x32_bf16(af4, buA, cin4, 0, 0, 0); \
        const float4v a5A = __builtin_amdgcn_mfma_f32_16x16x32_bf16(af5, buA, cin5, 0, 0, 0); \
        const float4v e0A = __builtin_amdgcn_mfma_f32_16x16x32_bf16(g0, b2A, a0A, 0, 0, 0); \
        const float4v e1A = __builtin_amdgcn_mfma_f32_16x16x32_bf16(g1, b2A, a1A, 0, 0, 0); \
        const float4v e2A = __builtin_amdgcn_mfma_f32_16x16x32_bf16(g2, b2A, a2A, 0, 0, 0); \
        const float4v e3A = __builtin_amdgcn_mfma_f32_16x16x32_bf16(g3, b2A, a3A, 0, 0, 0); \
        const float4v e4A = __builtin_amdgcn_mfma_f32_16x16x32_bf16(g4, b2A, cb4, 0, 0, 0); \
        const float4v e5A = __builtin_amdgcn_mfma_f32_16x16x32_bf16(g5, b2A, cb5, 0, 0, 0); \
        GATE_PAIR(h0a, LO2(e0A), LO2(e2A), LO2(a4A), LO2(e4A));                  \
        GATE_PAIR(h1a, HI2(e0A), HI2(e2A), HI2(a4A), HI2(e4A));                  \
        GATE_PAIR(h2a, LO2(e1A), LO2(e3A), LO2(a5A), LO2(e5A));                  \
        GATE_PAIR(h3a, HI2(e1A), HI2(e3A), HI2(a5A), HI2(e5A));                  \
        const float4v a0B = __builtin_amdgcn_mfma_f32_16x16x32_bf16(af0, buB, cin0, 0, 0, 0); \
        const float4v a1B = __builtin_amdgcn_mfma_f32_16x16x32_bf16(af1, buB, cin1, 0, 0, 0); \
        const float4v a2B = __builtin_amdgcn_mfma_f32_16x16x32_bf16(af2, buB, cin2, 0, 0, 0); \
        const float4v a3B = __builtin_amdgcn_mfma_f32_16x16x32_bf16(af3, buB, cin3, 0, 0, 0); \
        const float4v a4B = __builtin_amdgcn_mfma_f32_16x16x32_bf16(af4, buB, cin4, 0, 0, 0); \
        const float4v a5B = __builtin_amdgcn_mfma_f32_16x16x32_bf16(af5, buB, cin5, 0, 0, 0); \
        const float4v e0B = __builtin_amdgcn_mfma_f32_16x16x32_bf16(g0, b2B, a0B, 0, 0, 0); \
        const float4v e1B = __builtin_amdgcn_mfma_f32_16x16x32_bf16(g1, b2B, a1B, 0, 0, 0); \
        const float4v e2B = __builtin_amdgcn_mfma_f32_16x16x32_bf16(g2, b2B, a2B, 0, 0, 0); \
        const float4v e3B = __builtin_amdgcn_mfma_f32_16x16x32_bf16(g3, b2B, a3B, 0, 0, 0); \
        const float4v e4B = __builtin_amdgcn_mfma_f32_16x16x32_bf16(g4, b2B, cb4, 0, 0, 0); \
        const float4v e5B = __builtin_amdgcn_mfma_f32_16x16x32_bf16(g5, b2B, cb5, 0, 0, 0); \
        GATE_PAIR(h0b, LO2(e0B), LO2(e2B), LO2(a4B), LO2(e4B));                  \
        GATE_PAIR(h1b, HI2(e0B), HI2(e2B), HI2(a4B), HI2(e4B));                  \
        GATE_PAIR(h2b, LO2(e1B), LO2(e3B), LO2(a5B), LO2(e5B));                  \
        GATE_PAIR(h3b, HI2(e1B), HI2(e3B), HI2(a5B), HI2(e5B));                  \
    }

    #pragma unroll 1
    for (int t = 0; t < Tlen; t += 4) {
        GRU_STEP2(x0a, x0b); x0a = LOADXA(4); x0b = LOADXB(4);
        GRU_STEP2(x1a, x1b); x1a = LOADXA(5); x1b = LOADXB(5);
        GRU_STEP2(x2a, x2b); x2a = LOADXA(6); x2b = LOADXB(6);
        GRU_STEP2(x3a, x3b); x3a = LOADXA(7); x3b = LOADXB(7);
        if (USE_XT) { xta += 4 * Bsz; xtb += 4 * Bsz; }
        else        { xpa += 4 * Fnum; xpb += 4 * Fnum; }
    }

    float* __restrict__ oa = pre + (size_t)ba * (FPn * Hdim) + f * Hdim + 8 * S;
    oa[0] = h0a.x; oa[1] = h0a.y; oa[2] = h1a.x; oa[3] = h1a.y;
    oa[4] = h2a.x; oa[5] = h2a.y; oa[6] = h3a.x; oa[7] = h3a.y;
    float* __restrict__ ob = pre + (size_t)bb * (FPn * Hdim) + f * Hdim + 8 * S;
    ob[0] = h0b.x; ob[1] = h0b.y; ob[2] = h1b.x; ob[3] = h1b.y;
    ob[4] = h2b.x; ob[5] = h2b.y; ob[6] = h3b.x; ob[7] = h3b.y;
#undef GRU_STEP2
#undef GATE_PAIR
#undef LOADXA
#undef LOADXB
#undef LO2
#undef HI2
}

// ---------- epilogue: 4 waves/block, 1 wave per b.  lane = (h = l&31, f-halfset = l>>5)
__global__ __launch_bounds__(256)
void post_kernel(const float* __restrict__ pre,     // [B,18,32] (f<17 valid)
                 const float* __restrict__ statics, // [B,4]
                 const float* __restrict__ demoW,   // [32,4]
                 const float* __restrict__ demob,   // [32]
                 const float* __restrict__ lnw,     // [18,32]
                 const float* __restrict__ lnb,     // [18,32]
                 const float* __restrict__ protos,  // [8,576]
                 const float* __restrict__ pnorm,   // [8]
                 const float* __restrict__ Wq,      // [32,8]
                 const float* __restrict__ bq,      // [32]
                 const float* __restrict__ Wk,      // [8,18]
                 const float* __restrict__ bk,      // [8]
                 const float* __restrict__ Wv,      // [8,18]
                 const float* __restrict__ bv,      // [8]
                 const float* __restrict__ outW,    // [32]
                 const float* __restrict__ outb,    // [1]
                 float* __restrict__ out_logits,    // [B]
                 float* __restrict__ out_dist,      // [B,8]
                 float* __restrict__ out_ht)        // [B,18,32]
{
    const int b     = blockIdx.x * 4 + (threadIdx.x >> 6);
    const int l     = threadIdx.x & 63;
    const int hl    = l & 31;
    const int fbase = (l >> 5) * 9;

    float v[9];
    #pragma unroll
    for (int j = 0; j < 9; ++j) {
        const int fj = fbase + j;
        if (fj == 17) {
            float acc = demob[hl];
            #pragma unroll
            for (int d = 0; d < 4; ++d)
                acc = fmaf(statics[b * 4 + d], demoW[hl * 4 + d], acc);
            v[j] = acc;
        } else {
            v[j] = pre[(size_t)b * 576 + fj * 32 + hl];
        }
    }

    float s = 0.0f, ss = 0.0f;
    #pragma unroll
    for (int j = 0; j < 9; ++j) { s += v[j]; ss = fmaf(v[j], v[j], ss); }
    #pragma unroll
    for (int m = 32; m; m >>= 1) { s += __shfl_xor(s, m); ss += __shfl_xor(ss, m); }
    const float mu  = s * (1.0f / 576.0f);
    const float var = ss * (1.0f / 576.0f) - mu * mu;
    const float rs  = frsq(var + 1e-5f);

    float nrm = 0.0f;
    #pragma unroll
    for (int j = 0; j < 9; ++j) {
        const int fj = fbase + j;
        float y = fmaf((v[j] - mu) * rs, lnw[fj * 32 + hl], lnb[fj * 32 + hl]);
        v[j] = y;
        out_ht[(size_t)b * 576 + fj * 32 + hl] = y;
        nrm = fmaf(y, y, nrm);
    }
    #pragma unroll
    for (int m = 32; m; m >>= 1) nrm += __shfl_xor(nrm, m);
    nrm = sqrtf(nrm);

    float dist[8];
    #pragma unroll
    for (int p = 0; p < Pnum; ++p) {
        float d = 0.0f;
        #pragma unroll
        for (int j = 0; j < 9; ++j)
            d = fmaf(v[j], protos[p * 576 + (fbase + j) * 32 + hl], d);
        #pragma unroll
        for (int m = 32; m; m >>= 1) d += __shfl_xor(d, m);
        dist[p] = d / fmaxf(nrm * pnorm[p], 1e-8f);
    }
    if (l == 0) {
        #pragma unroll
        for (int p = 0; p < Pnum; ++p) out_dist[(size_t)b * Pnum + p] = dist[p];
    }

    float q = bq[hl];
    #pragma unroll
    for (int p = 0; p < Pnum; ++p) q = fmaf(dist[p], Wq[hl * 8 + p], q);
    float Sq = q;
    #pragma unroll
    for (int m = 16; m; m >>= 1) Sq += __shfl_xor(Sq, m);

    float sf[9], so[9];
    #pragma unroll
    for (int j = 0; j < 9; ++j) {
        float t = v[j] * q;
        #pragma unroll
        for (int m = 16; m; m >>= 1) t += __shfl_xor(t, m);
        sf[j] = t;
    }
    #pragma unroll
    for (int j = 0; j < 9; ++j) so[j] = __shfl_xor(sf[j], 32);
    const int obase = 9 - fbase;

    float e[8];
    #pragma unroll
    for (int p = 0; p < Pnum; ++p) {
        float a = bk[p] * Sq;
        #pragma unroll
        for (int j = 0; j < 9; ++j) {
            a = fmaf(sf[j], Wk[p * FPn + fbase + j], a);
            a = fmaf(so[j], Wk[p * FPn + obase + j], a);
        }
        e[p] = a;
    }
    float mx = e[0];
    #pragma unroll
    for (int p = 1; p < Pnum; ++p) mx = fmaxf(mx, e[p]);
    float aw[8], den = 0.0f;
    #pragma unroll
    for (int p = 0; p < Pnum; ++p) { aw[p] = __expf(e[p] - mx); den += aw[p]; }
    const float rden = frcp(den);
    #pragma unroll
    for (int p = 0; p < Pnum; ++p) aw[p] *= rden;

    float cc = 0.0f;
    #pragma unroll
    for (int p = 0; p < Pnum; ++p) cc = fmaf(aw[p], bv[p], cc);
    float vb = 0.0f;
    #pragma unroll
    for (int j = 0; j < 9; ++j) {
        float wv = 0.0f;
        #pragma unroll
        for (int p = 0; p < Pnum; ++p) wv = fmaf(aw[p], Wv[p * FPn + fbase + j], wv);
        vb = fmaf(v[j], wv, vb);
    }
    vb += __shfl_xor(vb, 32);
    vb += cc;

    float lg = vb * outW[hl];
    #pragma unroll
    for (int m = 16; m; m >>= 1) lg += __shfl_xor(lg, m);
    lg = fsigmoid(lg + outb[0]);
    if (l == 0) out_logits[b] = lg;
}

extern "C" void kernel_launch(void* const* d_in, const int* in_sizes, int n_in,
                              void* d_out, int out_size, void* d_ws, size_t ws_size,
                              hipStream_t stream) {
    const float* x      = (const float*)d_in[0];
    const float* statics= (const float*)d_in[1];
    const float* Wih    = (const float*)d_in[2];
    const float* Whh    = (const float*)d_in[3];
    const float* bih    = (const float*)d_in[4];
    const float* bhh    = (const float*)d_in[5];
    const float* demoW  = (const float*)d_in[6];
    const float* demob  = (const float*)d_in[7];
    const float* lnw    = (const float*)d_in[8];
    const float* lnb    = (const float*)d_in[9];
    const float* protos = (const float*)d_in[10];
    const float* Wq     = (const float*)d_in[11];
    const float* bq     = (const float*)d_in[12];
    const float* Wk     = (const float*)d_in[13];
    const float* bk     = (const float*)d_in[14];
    const float* Wv     = (const float*)d_in[15];
    const float* bv     = (const float*)d_in[16];
    const float* outW   = (const float*)d_in[17];
    const float* outb   = (const float*)d_in[18];

    // ws layout: pre[B*576] f32 | pnorm[8] f32 | xT[F,T+TPAD,B] bf16
    float* pre   = (float*)d_ws;
    float* pnorm = pre + (size_t)Bsz * FPn * Hdim;
    unsigned short* xT = (unsigned short*)(pnorm + 8);
    const size_t need = ((size_t)Bsz * FPn * Hdim + 8) * 4
                      + (size_t)Fnum * (Tlen + TPAD) * Bsz * 2;
    const bool use_xt = (ws_size >= need);

    prep_pnorm_kernel<<<dim3(1), dim3(256), 0, stream>>>(protos, pnorm);

    if (use_xt) {
        xpose_kernel<<<dim3(Bsz / 64, Tlen), dim3(64), 0, stream>>>(x, xT);
        gru_mfma_kernel<1><<<dim3(Bsz / 128, Fnum), dim3(256), 0, stream>>>(
            x, xT, Wih, Whh, bih, bhh, pre);
    } else {
        gru_mfma_kernel<0><<<dim3(Bsz / 128, Fnum), dim3(256), 0, stream>>>(
            x, xT, Wih, Whh, bih, bhh, pre);
    }

    float* out_logits = (float*)d_out;
    float* out_dist   = out_logits + Bsz;
    float* out_ht     = out_dist + (size_t)Bsz * Pnum;

    post_kernel<<<dim3(Bsz / 4), dim3(256), 0, stream>>>(
        pre, statics, demoW, demob, lnw, lnb, protos, pnorm,
        Wq, bq, Wk, bk, Wv, bv, outW, outb,
        out_logits, out_dist, out_ht);
}

// Round 12
// 896.826 us; speedup vs baseline: 2.0859x; 1.1116x over previous
//
#include <hip/hip_runtime.h>
#include <cmath>

#define Bsz  4096
#define Tlen 512
#define Fnum 17
#define Hdim 32
#define Pnum 8
#define FPn  18
#define G3   96   // 3*Hdim
#define TPAD 8    // extra xT rows so the depth-4 prefetch ring never reads OOB

#define L2E   1.4426950408889634f
#define NL2E (-1.4426950408889634f)
#define TL2E  2.8853900817779268f   // 2*log2(e)

typedef __attribute__((ext_vector_type(8))) short short8v;
typedef __attribute__((ext_vector_type(4))) float float4v;
typedef __attribute__((ext_vector_type(2))) float float2v;
typedef __attribute__((ext_vector_type(4))) unsigned uint4v;

__device__ __forceinline__ float frcp(float x)  { return __builtin_amdgcn_rcpf(x); }
__device__ __forceinline__ float frsq(float x)  { return __builtin_amdgcn_rsqf(x); }
__device__ __forceinline__ float fexp2(float x) { return __builtin_amdgcn_exp2f(x); }
__device__ __forceinline__ float fsigmoid(float x) {
    return frcp(1.0f + fexp2(NL2E * x));
}
__device__ __forceinline__ float2v fma2(float2v a, float2v b, float2v c) {
    return __builtin_elementwise_fma(a, b, c);
}
// well-defined fragment assembly (no union type-punning — R10/R11 lesson)
__device__ __forceinline__ short8v mk8(unsigned a, unsigned b, unsigned c, unsigned d) {
    uint4v v = {a, b, c, d};
    return __builtin_bit_cast(short8v, v);
}
// RNE float->bf16 bits
__device__ __forceinline__ short bf16b(float x) {
    unsigned u = __float_as_uint(x);
    unsigned r = (u + 0x7FFFu + ((u >> 16) & 1u)) >> 16;
    return (short)r;
}
// packed f32x2 -> bf16x2 (hardware RNE) — proven since R2
__device__ __forceinline__ unsigned cvtpk(float lo, float hi) {
    unsigned r;
    asm("v_cvt_pk_bf16_f32 %0, %1, %2" : "=v"(r) : "v"(lo), "v"(hi));
    return r;
}

// ---------- prep: prototype L2 norms ----------
__global__ void prep_pnorm_kernel(const float* __restrict__ protos, float* __restrict__ pnorm) {
    const int p    = threadIdx.x >> 5;
    const int lane = threadIdx.x & 31;
    float s = 0.0f;
    for (int j = lane; j < FPn * Hdim; j += 32) {
        float v = protos[p * FPn * Hdim + j];
        s = fmaf(v, v, s);
    }
    #pragma unroll
    for (int m = 16; m; m >>= 1) s += __shfl_xor(s, m);
    if (lane == 0) pnorm[p] = sqrtf(s);
}

// ---------- prep: x[B,T,F] -> xT[F,T+TPAD,B] in bf16 ----------
__global__ __launch_bounds__(64)
void xpose_kernel(const float* __restrict__ x, unsigned short* __restrict__ xT) {
    const int b = blockIdx.x * 64 + threadIdx.x;
    const int t = blockIdx.y;
    const float* __restrict__ xp = x + ((size_t)b * Tlen + t) * Fnum;
    #pragma unroll
    for (int ff = 0; ff < Fnum; ++ff)
        xT[(size_t)ff * (Tlen + TPAD) * Bsz + (size_t)t * Bsz + b] = (unsigned short)bf16b(xp[ff]);
}

// ---------- main GRU: un-chained MFMA + VALU ih -------------------------------
// Block = 4 waves; wave = (f, one 16-b tile)  [R5's proven 4352-wave shape].
// Set1 only: a_m = Ws@h + C1 (C1 = NL2E*(bih+bhh) for r,z; TL2E*bhh for n).
// ih contribution via per-lane fp32 constants (wr/wz/wn/bn), applied with pk-fma:
//   ar = wr*x + a_rz ; az = wz*x + a_z ; en = wn*x + bn   — removes the 6
//   chained set-2 MFMAs (shorter serial chain, -6 MFMA issue).
// pi(m,rr) = (m>>1)*32 + 8*(rr>>2) + (m&1)*4 + (rr&3)  [R2-validated]
// => lane (c,S) tile m reg q holds gate unit j = 8S+(m&1)*4+q of its own b;
//    LO/HI float2 pairs of a_m line up with wih[g*32+8S+2u] pairs.
// Gate combine (R5 algebra + shared denominator rcp): E=e^{2y}, ez=e^{-zhat}:
//   h' = [ez*(E-1) + h*(E+1)] / [(E+1)*(1+ez)],  R = rcp(den.x*den.y)
// Codegen rules: bit_cast fragments (R10/R11), built inside the step (R8),
// no setprio (R9), no hoisted partial aggregates (R8).
template<int USE_XT>
__global__ __launch_bounds__(256, 4)
void gru_mfma_kernel(const float* __restrict__ x,
                     const unsigned short* __restrict__ xT,
                     const float* __restrict__ Wih,   // [F,96]
                     const float* __restrict__ Whh,   // [F,96,32]
                     const float* __restrict__ bih,   // [F,96]
                     const float* __restrict__ bhh,   // [F,96]
                     float* __restrict__ pre)         // [B,18,32]
{
    const int f  = blockIdx.y;
    const int wv = threadIdx.x >> 6;
    const int l  = threadIdx.x & 63;
    const int c  = l & 15, S = l >> 4;
    const int b  = blockIdx.x * 64 + wv * 16 + c;

    const float* __restrict__ whh_f = Whh + (size_t)f * G3 * Hdim;
    const float* __restrict__ wih_f = Wih + (size_t)f * G3;
    const float* __restrict__ bih_f = bih + (size_t)f * G3;
    const float* __restrict__ bhh_f = bhh + (size_t)f * G3;

    // ---- one-time per-lane constants ----
    short8v af0, af1, af2, af3, af4, af5;       // Whh fragments (set1)
    float4v cin0, cin1, cin2, cin3, cin4, cin5; // fp32 set1 C (bias)
    {
        #pragma unroll
        for (int m = 0; m < 6; ++m) {
            const int gate = m >> 1;
            const float sc = (gate < 2) ? NL2E : TL2E;
            const int gA = gate * 32 + 8 * (c >> 2) + (m & 1) * 4 + (c & 3);
            const float* wrow = whh_f + (size_t)gA * Hdim + 8 * S;
            short8v af = mk8(cvtpk(wrow[0] * sc, wrow[1] * sc),
                             cvtpk(wrow[2] * sc, wrow[3] * sc),
                             cvtpk(wrow[4] * sc, wrow[5] * sc),
                             cvtpk(wrow[6] * sc, wrow[7] * sc));
            float4v ci;
            #pragma unroll
            for (int q = 0; q < 4; ++q) {
                const int gC = gate * 32 + 8 * S + (m & 1) * 4 + q;
                ci[q] = (gate < 2) ? NL2E * (bhh_f[gC] + bih_f[gC])
                                   : TL2E * bhh_f[gC];
            }
            if (m == 0) { af0 = af; cin0 = ci; }
            if (m == 1) { af1 = af; cin1 = ci; }
            if (m == 2) { af2 = af; cin2 = ci; }
            if (m == 3) { af3 = af; cin3 = ci; }
            if (m == 4) { af4 = af; cin4 = ci; }
            if (m == 5) { af5 = af; cin5 = ci; }
        }
    }
    // per-lane ih constants, float2 pairs over units j = 8S+2u, 8S+2u+1
    float2v wr0, wr1, wr2, wr3, wz0, wz1, wz2, wz3;
    float2v wn0, wn1, wn2, wn3, bn0, bn1, bn2, bn3;
    {
        const int j0 = 8 * S;
        wr0 = (float2v){NL2E * wih_f[j0 + 0], NL2E * wih_f[j0 + 1]};
        wr1 = (float2v){NL2E * wih_f[j0 + 2], NL2E * wih_f[j0 + 3]};
        wr2 = (float2v){NL2E * wih_f[j0 + 4], NL2E * wih_f[j0 + 5]};
        wr3 = (float2v){NL2E * wih_f[j0 + 6], NL2E * wih_f[j0 + 7]};
        wz0 = (float2v){NL2E * wih_f[32 + j0 + 0], NL2E * wih_f[32 + j0 + 1]};
        wz1 = (float2v){NL2E * wih_f[32 + j0 + 2], NL2E * wih_f[32 + j0 + 3]};
        wz2 = (float2v){NL2E * wih_f[32 + j0 + 4], NL2E * wih_f[32 + j0 + 5]};
        wz3 = (float2v){NL2E * wih_f[32 + j0 + 6], NL2E * wih_f[32 + j0 + 7]};
        wn0 = (float2v){TL2E * wih_f[64 + j0 + 0], TL2E * wih_f[64 + j0 + 1]};
        wn1 = (float2v){TL2E * wih_f[64 + j0 + 2], TL2E * wih_f[64 + j0 + 3]};
        wn2 = (float2v){TL2E * wih_f[64 + j0 + 4], TL2E * wih_f[64 + j0 + 5]};
        wn3 = (float2v){TL2E * wih_f[64 + j0 + 6], TL2E * wih_f[64 + j0 + 7]};
        bn0 = (float2v){TL2E * bih_f[64 + j0 + 0], TL2E * bih_f[64 + j0 + 1]};
        bn1 = (float2v){TL2E * bih_f[64 + j0 + 2], TL2E * bih_f[64 + j0 + 3]};
        bn2 = (float2v){TL2E * bih_f[64 + j0 + 4], TL2E * bih_f[64 + j0 + 5]};
        bn3 = (float2v){TL2E * bih_f[64 + j0 + 6], TL2E * bih_f[64 + j0 + 7]};
    }

    float2v h0 = {0,0}, h1 = {0,0}, h2 = {0,0}, h3 = {0,0};

    // ---- x prefetch ring, depth 4 (phase-relative offsets) ----
    const unsigned short* xtp = USE_XT ? (xT + (size_t)f * (Tlen + TPAD) * Bsz + b) : nullptr;
    const float* xp = USE_XT ? nullptr : (x + (size_t)b * Tlen * Fnum + f);
    float x0, x1, x2, x3;
    if (USE_XT) {
        x0 = __uint_as_float(((unsigned)xtp[0 * Bsz]) << 16);
        x1 = __uint_as_float(((unsigned)xtp[1 * Bsz]) << 16);
        x2 = __uint_as_float(((unsigned)xtp[2 * Bsz]) << 16);
        x3 = __uint_as_float(((unsigned)xtp[3 * Bsz]) << 16);
    } else {
        x0 = xp[0 * Fnum]; x1 = xp[1 * Fnum]; x2 = xp[2 * Fnum]; x3 = xp[3 * Fnum];
    }

// ph is relative to the CURRENT xtp/xp (which corresponds to loop time t)
#define LOADX(ph) (USE_XT ? __uint_as_float(((unsigned)xtp[(size_t)(ph) * Bsz]) << 16) \
                          : ((t + (ph) < Tlen) ? xp[(size_t)(ph) * Fnum] : 0.0f))

// R5 gate algebra + shared denominator rcp (1 rcp instead of 2 for the divide)
#define GATE_PAIR(hp, ar, az, an, en)                                           \
    {                                                                           \
        const float2v _ar = (ar), _az = (az), _an = (an), _en = (en);           \
        float2v er = {fexp2(_ar.x), fexp2(_ar.y)};                              \
        float2v rp = er + (float2v){1.0f, 1.0f};                                \
        float2v r  = {frcp(rp.x), frcp(rp.y)};                                  \
        float2v ez = {fexp2(_az.x), fexp2(_az.y)};                              \
        float2v y  = fma2(r, _an, _en);                                         \
        float2v E  = {fexp2(y.x), fexp2(y.y)};                                  \
        float2v num = fma2(ez, E, -ez) + fma2(hp, E, hp);                       \
        float2v den = (E + (float2v){1.0f, 1.0f}) * (ez + (float2v){1.0f, 1.0f});\
        const float R = frcp(den.x * den.y);                                    \
        hp = (float2v){num.x * (den.y * R), num.y * (den.x * R)};               \
    }

#define LO2(v) ((float2v){(v)[0], (v)[1]})
#define HI2(v) ((float2v){(v)[2], (v)[3]})

#define GRU_STEP(xv)                                                             \
    {                                                                            \
        const short8v bu = mk8(cvtpk(h0.x, h0.y), cvtpk(h1.x, h1.y),             \
                               cvtpk(h2.x, h2.y), cvtpk(h3.x, h3.y));            \
        const float4v a0 = __builtin_amdgcn_mfma_f32_16x16x32_bf16(af0, bu, cin0, 0, 0, 0); \
        const float4v a1 = __builtin_amdgcn_mfma_f32_16x16x32_bf16(af1, bu, cin1, 0, 0, 0); \
        const float4v a2 = __builtin_amdgcn_mfma_f32_16x16x32_bf16(af2, bu, cin2, 0, 0, 0); \
        const float4v a3 = __builtin_amdgcn_mfma_f32_16x16x32_bf16(af3, bu, cin3, 0, 0, 0); \
        const float4v a4 = __builtin_amdgcn_mfma_f32_16x16x32_bf16(af4, bu, cin4, 0, 0, 0); \
        const float4v a5 = __builtin_amdgcn_mfma_f32_16x16x32_bf16(af5, bu, cin5, 0, 0, 0); \
        const float2v x2v = {(xv), (xv)};                                        \
        GATE_PAIR(h0, fma2(wr0, x2v, LO2(a0)), fma2(wz0, x2v, LO2(a2)),          \
                      LO2(a4),                 fma2(wn0, x2v, bn0));             \
        GATE_PAIR(h1, fma2(wr1, x2v, HI2(a0)), fma2(wz1, x2v, HI2(a2)),          \
                      HI2(a4),                 fma2(wn1, x2v, bn1));             \
        GATE_PAIR(h2, fma2(wr2, x2v, LO2(a1)), fma2(wz2, x2v, LO2(a3)),          \
                      LO2(a5),                 fma2(wn2, x2v, bn2));             \
        GATE_PAIR(h3, fma2(wr3, x2v, HI2(a1)), fma2(wz3, x2v, HI2(a3)),          \
                      HI2(a5),                 fma2(wn3, x2v, bn3));             \
    }

    #pragma unroll 1
    for (int t = 0; t < Tlen; t += 4) {
        GRU_STEP(x0); x0 = LOADX(4);
        GRU_STEP(x1); x1 = LOADX(5);
        GRU_STEP(x2); x2 = LOADX(6);
        GRU_STEP(x3); x3 = LOADX(7);
        if (USE_XT) xtp += 4 * Bsz; else xp += 4 * Fnum;
    }

    float* __restrict__ o = pre + (size_t)b * (FPn * Hdim) + f * Hdim + 8 * S;
    o[0] = h0.x; o[1] = h0.y; o[2] = h1.x; o[3] = h1.y;
    o[4] = h2.x; o[5] = h2.y; o[6] = h3.x; o[7] = h3.y;
#undef GRU_STEP
#undef GATE_PAIR
#undef LOADX
#undef LO2
#undef HI2
}

// ---------- epilogue: 4 waves/block, 1 wave per b.  lane = (h = l&31, f-halfset = l>>5)
__global__ __launch_bounds__(256)
void post_kernel(const float* __restrict__ pre,     // [B,18,32] (f<17 valid)
                 const float* __restrict__ statics, // [B,4]
                 const float* __restrict__ demoW,   // [32,4]
                 const float* __restrict__ demob,   // [32]
                 const float* __restrict__ lnw,     // [18,32]
                 const float* __restrict__ lnb,     // [18,32]
                 const float* __restrict__ protos,  // [8,576]
                 const float* __restrict__ pnorm,   // [8]
                 const float* __restrict__ Wq,      // [32,8]
                 const float* __restrict__ bq,      // [32]
                 const float* __restrict__ Wk,      // [8,18]
                 const float* __restrict__ bk,      // [8]
                 const float* __restrict__ Wv,      // [8,18]
                 const float* __restrict__ bv,      // [8]
                 const float* __restrict__ outW,    // [32]
                 const float* __restrict__ outb,    // [1]
                 float* __restrict__ out_logits,    // [B]
                 float* __restrict__ out_dist,      // [B,8]
                 float* __restrict__ out_ht)        // [B,18,32]
{
    const int b     = blockIdx.x * 4 + (threadIdx.x >> 6);
    const int l     = threadIdx.x & 63;
    const int hl    = l & 31;
    const int fbase = (l >> 5) * 9;

    float v[9];
    #pragma unroll
    for (int j = 0; j < 9; ++j) {
        const int fj = fbase + j;
        if (fj == 17) {
            float acc = demob[hl];
            #pragma unroll
            for (int d = 0; d < 4; ++d)
                acc = fmaf(statics[b * 4 + d], demoW[hl * 4 + d], acc);
            v[j] = acc;
        } else {
            v[j] = pre[(size_t)b * 576 + fj * 32 + hl];
        }
    }

    float s = 0.0f, ss = 0.0f;
    #pragma unroll
    for (int j = 0; j < 9; ++j) { s += v[j]; ss = fmaf(v[j], v[j], ss); }
    #pragma unroll
    for (int m = 32; m; m >>= 1) { s += __shfl_xor(s, m); ss += __shfl_xor(ss, m); }
    const float mu  = s * (1.0f / 576.0f);
    const float var = ss * (1.0f / 576.0f) - mu * mu;
    const float rs  = frsq(var + 1e-5f);

    float nrm = 0.0f;
    #pragma unroll
    for (int j = 0; j < 9; ++j) {
        const int fj = fbase + j;
        float y = fmaf((v[j] - mu) * rs, lnw[fj * 32 + hl], lnb[fj * 32 + hl]);
        v[j] = y;
        out_ht[(size_t)b * 576 + fj * 32 + hl] = y;
        nrm = fmaf(y, y, nrm);
    }
    #pragma unroll
    for (int m = 32; m; m >>= 1) nrm += __shfl_xor(nrm, m);
    nrm = sqrtf(nrm);

    float dist[8];
    #pragma unroll
    for (int p = 0; p < Pnum; ++p) {
        float d = 0.0f;
        #pragma unroll
        for (int j = 0; j < 9; ++j)
            d = fmaf(v[j], protos[p * 576 + (fbase + j) * 32 + hl], d);
        #pragma unroll
        for (int m = 32; m; m >>= 1) d += __shfl_xor(d, m);
        dist[p] = d / fmaxf(nrm * pnorm[p], 1e-8f);
    }
    if (l == 0) {
        #pragma unroll
        for (int p = 0; p < Pnum; ++p) out_dist[(size_t)b * Pnum + p] = dist[p];
    }

    float q = bq[hl];
    #pragma unroll
    for (int p = 0; p < Pnum; ++p) q = fmaf(dist[p], Wq[hl * 8 + p], q);
    float Sq = q;
    #pragma unroll
    for (int m = 16; m; m >>= 1) Sq += __shfl_xor(Sq, m);

    float sf[9], so[9];
    #pragma unroll
    for (int j = 0; j < 9; ++j) {
        float t = v[j] * q;
        #pragma unroll
        for (int m = 16; m; m >>= 1) t += __shfl_xor(t, m);
        sf[j] = t;
    }
    #pragma unroll
    for (int j = 0; j < 9; ++j) so[j] = __shfl_xor(sf[j], 32);
    const int obase = 9 - fbase;

    float e[8];
    #pragma unroll
    for (int p = 0; p < Pnum; ++p) {
        float a = bk[p] * Sq;
        #pragma unroll
        for (int j = 0; j < 9; ++j) {
            a = fmaf(sf[j], Wk[p * FPn + fbase + j], a);
            a = fmaf(so[j], Wk[p * FPn + obase + j], a);
        }
        e[p] = a;
    }
    float mx = e[0];
    #pragma unroll
    for (int p = 1; p < Pnum; ++p) mx = fmaxf(mx, e[p]);
    float aw[8], den = 0.0f;
    #pragma unroll
    for (int p = 0; p < Pnum; ++p) { aw[p] = __expf(e[p] - mx); den += aw[p]; }
    const float rden = frcp(den);
    #pragma unroll
    for (int p = 0; p < Pnum; ++p) aw[p] *= rden;

    float cc = 0.0f;
    #pragma unroll
    for (int p = 0; p < Pnum; ++p) cc = fmaf(aw[p], bv[p], cc);
    float vb = 0.0f;
    #pragma unroll
    for (int j = 0; j < 9; ++j) {
        float wv = 0.0f;
        #pragma unroll
        for (int p = 0; p < Pnum; ++p) wv = fmaf(aw[p], Wv[p * FPn + fbase + j], wv);
        vb = fmaf(v[j], wv, vb);
    }
    vb += __shfl_xor(vb, 32);
    vb += cc;

    float lg = vb * outW[hl];
    #pragma unroll
    for (int m = 16; m; m >>= 1) lg += __shfl_xor(lg, m);
    lg = fsigmoid(lg + outb[0]);
    if (l == 0) out_logits[b] = lg;
}

extern "C" void kernel_launch(void* const* d_in, const int* in_sizes, int n_in,
                              void* d_out, int out_size, void* d_ws, size_t ws_size,
                              hipStream_t stream) {
    const float* x      = (const float*)d_in[0];
    const float* statics= (const float*)d_in[1];
    const float* Wih    = (const float*)d_in[2];
    const float* Whh    = (const float*)d_in[3];
    const float* bih    = (const float*)d_in[4];
    const float* bhh    = (const float*)d_in[5];
    const float* demoW  = (const float*)d_in[6];
    const float* demob  = (const float*)d_in[7];
    const float* lnw    = (const float*)d_in[8];
    const float* lnb    = (const float*)d_in[9];
    const float* protos = (const float*)d_in[10];
    const float* Wq     = (const float*)d_in[11];
    const float* bq     = (const float*)d_in[12];
    const float* Wk     = (const float*)d_in[13];
    const float* bk     = (const float*)d_in[14];
    const float* Wv     = (const float*)d_in[15];
    const float* bv     = (const float*)d_in[16];
    const float* outW   = (const float*)d_in[17];
    const float* outb   = (const float*)d_in[18];

    // ws layout: pre[B*576] f32 | pnorm[8] f32 | xT[F,T+TPAD,B] bf16
    float* pre   = (float*)d_ws;
    float* pnorm = pre + (size_t)Bsz * FPn * Hdim;
    unsigned short* xT = (unsigned short*)(pnorm + 8);
    const size_t need = ((size_t)Bsz * FPn * Hdim + 8) * 4
                      + (size_t)Fnum * (Tlen + TPAD) * Bsz * 2;
    const bool use_xt = (ws_size >= need);

    prep_pnorm_kernel<<<dim3(1), dim3(256), 0, stream>>>(protos, pnorm);

    if (use_xt) {
        xpose_kernel<<<dim3(Bsz / 64, Tlen), dim3(64), 0, stream>>>(x, xT);
        gru_mfma_kernel<1><<<dim3(Bsz / 64, Fnum), dim3(256), 0, stream>>>(
            x, xT, Wih, Whh, bih, bhh, pre);
    } else {
        gru_mfma_kernel<0><<<dim3(Bsz / 64, Fnum), dim3(256), 0, stream>>>(
            x, xT, Wih, Whh, bih, bhh, pre);
    }

    float* out_logits = (float*)d_out;
    float* out_dist   = out_logits + Bsz;
    float* out_ht     = out_dist + (size_t)Bsz * Pnum;

    post_kernel<<<dim3(Bsz / 4), dim3(256), 0, stream>>>(
        pre, statics, demoW, demob, lnw, lnb, protos, pnorm,
        Wq, bq, Wk, bk, Wv, bv, outW, outb,
        out_logits, out_dist, out_ht);
}

// Round 13
// 841.431 us; speedup vs baseline: 2.2233x; 1.0658x over previous
//
#include <hip/hip_runtime.h>
#include <cmath>

#define Bsz  4096
#define Tlen 512
#define Fnum 17
#define Hdim 32
#define Pnum 8
#define FPn  18
#define G3   96   // 3*Hdim
#define TPAD 8    // extra xT rows so the depth-4 prefetch ring never reads OOB

#define L2E   1.4426950408889634f
#define NL2E (-1.4426950408889634f)
#define TL2E  2.8853900817779268f   // 2*log2(e)

typedef __attribute__((ext_vector_type(8))) short short8v;
typedef __attribute__((ext_vector_type(4))) float float4v;
typedef __attribute__((ext_vector_type(2))) float float2v;

__device__ __forceinline__ float frcp(float x)  { return __builtin_amdgcn_rcpf(x); }
__device__ __forceinline__ float frsq(float x)  { return __builtin_amdgcn_rsqf(x); }
__device__ __forceinline__ float fexp2(float x) { return __builtin_amdgcn_exp2f(x); }
__device__ __forceinline__ float fsigmoid(float x) {
    return frcp(1.0f + fexp2(NL2E * x));
}
// compiler-packed f32 pair ops (backend may select v_pk_* for v2f32 — no inline asm)
__device__ __forceinline__ float2v fma2(float2v a, float2v b, float2v c) {
    return __builtin_elementwise_fma(a, b, c);
}
// RNE float->bf16 bits
__device__ __forceinline__ short bf16b(float x) {
    unsigned u = __float_as_uint(x);
    unsigned r = (u + 0x7FFFu + ((u >> 16) & 1u)) >> 16;
    return (short)r;
}
// packed f32x2 -> bf16x2 (hardware RNE) — proven since R2
__device__ __forceinline__ unsigned cvtpk(float lo, float hi) {
    unsigned r;
    asm("v_cvt_pk_bf16_f32 %0, %1, %2" : "=v"(r) : "v"(lo), "v"(hi));
    return r;
}

// ---------- prep: prototype L2 norms ----------
__global__ void prep_pnorm_kernel(const float* __restrict__ protos, float* __restrict__ pnorm) {
    const int p    = threadIdx.x >> 5;
    const int lane = threadIdx.x & 31;
    float s = 0.0f;
    for (int j = lane; j < FPn * Hdim; j += 32) {
        float v = protos[p * FPn * Hdim + j];
        s = fmaf(v, v, s);
    }
    #pragma unroll
    for (int m = 16; m; m >>= 1) s += __shfl_xor(s, m);
    if (lane == 0) pnorm[p] = sqrtf(s);
}

// ---------- prep: x[B,T,F] -> xT[F,T+TPAD,B] in bf16 ----------
__global__ __launch_bounds__(64)
void xpose_kernel(const float* __restrict__ x, unsigned short* __restrict__ xT) {
    const int b = blockIdx.x * 64 + threadIdx.x;
    const int t = blockIdx.y;
    const float* __restrict__ xp = x + ((size_t)b * Tlen + t) * Fnum;
    #pragma unroll
    for (int ff = 0; ff < Fnum; ++ff)
        xT[(size_t)ff * (Tlen + TPAD) * Bsz + (size_t)t * Bsz + b] = (unsigned short)bf16b(xp[ff]);
}

// ---------- main GRU via chained MFMA (R5-proven math) ------------------------
// Block = 4 waves; wave = (f, 16-b tile)   [R5's proven shape, 4352 waves].
// Set1: a_m = Ws@h + C1  (C1 = fp32 bias: NL2E*(bih+bhh) for r,z; TL2E*bhh for n)
// Set2 (chained): e_m = Wx@[x] + a_m  for r,z; e_n = Wx@[x] + TL2E*bih_n for n.
// pi(m,rr) = (m>>1)*32 + 8*(rr>>2) + (m&1)*4 + (rr&3)  [R2-validated]
// Gate combine (R5 exact form): E=e^{2y}, ez=e^{-zhat}:
//   h' = [ez*(E-1) + h*(E+1)] / [(E+1)*(1+ez)]   (per-element rcp)
// Codegen rules learned: fragments built fresh inside the step (R8: hoisted
// partial unions spill 3.3GB); NO setprio (R9: fences 12-MFMA cluster -> spill);
// chained MFMA beats VALU-ih (R12: MFMA issue is free, VALU is the bottleneck).
// NEW (R13): raw-bits x-feed (bit-identical, R9-exonerated) + s_sleep entry
// stagger to break the co-SIMD trans-unit convoy.
template<int USE_XT>
__global__ __launch_bounds__(256, 4)
void gru_mfma_kernel(const float* __restrict__ x,
                     const unsigned short* __restrict__ xT,
                     const float* __restrict__ Wih,   // [F,96]
                     const float* __restrict__ Whh,   // [F,96,32]
                     const float* __restrict__ bih,   // [F,96]
                     const float* __restrict__ bhh,   // [F,96]
                     float* __restrict__ pre)         // [B,18,32]
{
    // de-sync waves on a SIMD (blocks co-resident on a CU have different
    // blockIdx.x): 0..7 × ~64cyc stagger; timing-only, output-deterministic.
    for (int i = (blockIdx.x & 7); i > 0; --i) __builtin_amdgcn_s_sleep(1);

    const int f  = blockIdx.y;
    const int wv = threadIdx.x >> 6;
    const int l  = threadIdx.x & 63;
    const int c  = l & 15, S = l >> 4;
    const int b  = blockIdx.x * 64 + wv * 16 + c;

    const float* __restrict__ whh_f = Whh + (size_t)f * G3 * Hdim;
    const float* __restrict__ wih_f = Wih + (size_t)f * G3;
    const float* __restrict__ bih_f = bih + (size_t)f * G3;
    const float* __restrict__ bhh_f = bhh + (size_t)f * G3;

    // ---- one-time per-lane constants ----
    short8v af0, af1, af2, af3, af4, af5;       // Whh fragments (set1)
    short8v g0, g1, g2, g3, g4, g5;             // Wih fragments (set2, k=0 col)
    float4v cin0, cin1, cin2, cin3, cin4, cin5; // fp32 set1 C (bias)
    float4v cb4, cb5;                           // fp32 set2 C for n tiles
    {
        union { short8v s; unsigned u[4]; } au, gu;
        #pragma unroll
        for (int m = 0; m < 6; ++m) {
            const int gate = m >> 1;
            const float sc = (gate < 2) ? NL2E : TL2E;
            const int gA = gate * 32 + 8 * (c >> 2) + (m & 1) * 4 + (c & 3);
            const float* wrow = whh_f + (size_t)gA * Hdim + 8 * S;
            #pragma unroll
            for (int u = 0; u < 4; ++u)
                au.u[u] = cvtpk(wrow[2 * u] * sc, wrow[2 * u + 1] * sc);
            gu.u[0] = (S == 0) ? cvtpk(sc * wih_f[gA], 0.0f) : 0u;
            gu.u[1] = 0u; gu.u[2] = 0u; gu.u[3] = 0u;
            float4v ci;
            #pragma unroll
            for (int q = 0; q < 4; ++q) {
                const int gC = gate * 32 + 8 * S + (m & 1) * 4 + q;
                ci[q] = (gate < 2) ? NL2E * (bhh_f[gC] + bih_f[gC])
                                   : TL2E * bhh_f[gC];
            }
            if (m == 0) { af0 = au.s; g0 = gu.s; cin0 = ci; }
            if (m == 1) { af1 = au.s; g1 = gu.s; cin1 = ci; }
            if (m == 2) { af2 = au.s; g2 = gu.s; cin2 = ci; }
            if (m == 3) { af3 = au.s; g3 = gu.s; cin3 = ci; }
            if (m == 4) { af4 = au.s; g4 = gu.s; cin4 = ci; }
            if (m == 5) { af5 = au.s; g5 = gu.s; cin5 = ci; }
        }
        #pragma unroll
        for (int q = 0; q < 4; ++q) {
            cb4[q] = TL2E * bih_f[64 + 8 * S + q];
            cb5[q] = TL2E * bih_f[64 + 8 * S + 4 + q];
        }
    }
    const unsigned msk = (S == 0) ? 0xFFFFu : 0u;   // only S=0 lanes feed k=0 of B2

    float2v h0 = {0,0}, h1 = {0,0}, h2 = {0,0}, h3 = {0,0};

    // ---- x prefetch ring, depth 4 (phase-relative offsets), raw bf16 bits ----
    const unsigned short* xtp = USE_XT ? (xT + (size_t)f * (Tlen + TPAD) * Bsz + b) : nullptr;
    const float* xp = USE_XT ? nullptr : (x + (size_t)b * Tlen * Fnum + f);
    unsigned x0, x1, x2, x3;
    if (USE_XT) {
        x0 = xtp[0 * Bsz]; x1 = xtp[1 * Bsz]; x2 = xtp[2 * Bsz]; x3 = xtp[3 * Bsz];
    } else {
        x0 = (unsigned short)bf16b(xp[0 * Fnum]);
        x1 = (unsigned short)bf16b(xp[1 * Fnum]);
        x2 = (unsigned short)bf16b(xp[2 * Fnum]);
        x3 = (unsigned short)bf16b(xp[3 * Fnum]);
    }

// ph is relative to the CURRENT xtp/xp (which corresponds to loop time t)
#define LOADX(ph) (USE_XT ? (unsigned)xtp[(size_t)(ph) * Bsz]                        \
                          : ((t + (ph) < Tlen) ? (unsigned)(unsigned short)bf16b(xp[(size_t)(ph) * Fnum]) : 0u))

// R5-proven gate combine, per packed pair (verbatim)
#define GATE_PAIR(hp, ar, az, an, en)                                           \
    {                                                                           \
        const float2v _ar = (ar), _az = (az), _an = (an), _en = (en);           \
        float2v er = {fexp2(_ar.x), fexp2(_ar.y)};                              \
        float2v rp = er + (float2v){1.0f, 1.0f};                                \
        float2v r  = {frcp(rp.x), frcp(rp.y)};                                  \
        float2v ez = {fexp2(_az.x), fexp2(_az.y)};                              \
        float2v y  = fma2(r, _an, _en);                                         \
        float2v E  = {fexp2(y.x), fexp2(y.y)};                                  \
        float2v num = fma2(ez, E, -ez) + fma2(hp, E, hp);                       \
        float2v den = (E + (float2v){1.0f, 1.0f}) * (ez + (float2v){1.0f, 1.0f});\
        float2v rd = {frcp(den.x), frcp(den.y)};                                \
        hp = num * rd;                                                          \
    }

#define LO2(v) ((float2v){(v)[0], (v)[1]})
#define HI2(v) ((float2v){(v)[2], (v)[3]})

#define GRU_STEP(xbits)                                                          \
    {                                                                            \
        union { short8v s; unsigned u[4]; } bu;                                  \
        bu.u[0] = cvtpk(h0.x, h0.y);                                             \
        bu.u[1] = cvtpk(h1.x, h1.y);                                             \
        bu.u[2] = cvtpk(h2.x, h2.y);                                             \
        bu.u[3] = cvtpk(h3.x, h3.y);                                             \
        union { short8v s; unsigned u[4]; } b2;                                  \
        b2.u[0] = (xbits) & msk;                                                 \
        b2.u[1] = 0u; b2.u[2] = 0u; b2.u[3] = 0u;                                \
        const float4v a0 = __builtin_amdgcn_mfma_f32_16x16x32_bf16(af0, bu.s, cin0, 0, 0, 0); \
        const float4v a1 = __builtin_amdgcn_mfma_f32_16x16x32_bf16(af1, bu.s, cin1, 0, 0, 0); \
        const float4v a2 = __builtin_amdgcn_mfma_f32_16x16x32_bf16(af2, bu.s, cin2, 0, 0, 0); \
        const float4v a3 = __builtin_amdgcn_mfma_f32_16x16x32_bf16(af3, bu.s, cin3, 0, 0, 0); \
        const float4v a4 = __builtin_amdgcn_mfma_f32_16x16x32_bf16(af4, bu.s, cin4, 0, 0, 0); \
        const float4v a5 = __builtin_amdgcn_mfma_f32_16x16x32_bf16(af5, bu.s, cin5, 0, 0, 0); \
        const float4v e0 = __builtin_amdgcn_mfma_f32_16x16x32_bf16(g0, b2.s, a0, 0, 0, 0); \
        const float4v e1 = __builtin_amdgcn_mfma_f32_16x16x32_bf16(g1, b2.s, a1, 0, 0, 0); \
        const float4v e2 = __builtin_amdgcn_mfma_f32_16x16x32_bf16(g2, b2.s, a2, 0, 0, 0); \
        const float4v e3 = __builtin_amdgcn_mfma_f32_16x16x32_bf16(g3, b2.s, a3, 0, 0, 0); \
        const float4v e4 = __builtin_amdgcn_mfma_f32_16x16x32_bf16(g4, b2.s, cb4, 0, 0, 0); \
        const float4v e5 = __builtin_amdgcn_mfma_f32_16x16x32_bf16(g5, b2.s, cb5, 0, 0, 0); \
        GATE_PAIR(h0, LO2(e0), LO2(e2), LO2(a4), LO2(e4));                       \
        GATE_PAIR(h1, HI2(e0), HI2(e2), HI2(a4), HI2(e4));                       \
        GATE_PAIR(h2, LO2(e1), LO2(e3), LO2(a5), LO2(e5));                       \
        GATE_PAIR(h3, HI2(e1), HI2(e3), HI2(a5), HI2(e5));                       \
    }

    #pragma unroll 1
    for (int t = 0; t < Tlen; t += 4) {
        GRU_STEP(x0); x0 = LOADX(4);
        GRU_STEP(x1); x1 = LOADX(5);
        GRU_STEP(x2); x2 = LOADX(6);
        GRU_STEP(x3); x3 = LOADX(7);
        if (USE_XT) xtp += 4 * Bsz; else xp += 4 * Fnum;
    }

    float* __restrict__ o = pre + (size_t)b * (FPn * Hdim) + f * Hdim + 8 * S;
    o[0] = h0.x; o[1] = h0.y; o[2] = h1.x; o[3] = h1.y;
    o[4] = h2.x; o[5] = h2.y; o[6] = h3.x; o[7] = h3.y;
#undef GRU_STEP
#undef GATE_PAIR
#undef LOADX
#undef LO2
#undef HI2
}

// ---------- epilogue: 4 waves/block, 1 wave per b.  lane = (h = l&31, f-halfset = l>>5)
__global__ __launch_bounds__(256)
void post_kernel(const float* __restrict__ pre,     // [B,18,32] (f<17 valid)
                 const float* __restrict__ statics, // [B,4]
                 const float* __restrict__ demoW,   // [32,4]
                 const float* __restrict__ demob,   // [32]
                 const float* __restrict__ lnw,     // [18,32]
                 const float* __restrict__ lnb,     // [18,32]
                 const float* __restrict__ protos,  // [8,576]
                 const float* __restrict__ pnorm,   // [8]
                 const float* __restrict__ Wq,      // [32,8]
                 const float* __restrict__ bq,      // [32]
                 const float* __restrict__ Wk,      // [8,18]
                 const float* __restrict__ bk,      // [8]
                 const float* __restrict__ Wv,      // [8,18]
                 const float* __restrict__ bv,      // [8]
                 const float* __restrict__ outW,    // [32]
                 const float* __restrict__ outb,    // [1]
                 float* __restrict__ out_logits,    // [B]
                 float* __restrict__ out_dist,      // [B,8]
                 float* __restrict__ out_ht)        // [B,18,32]
{
    const int b     = blockIdx.x * 4 + (threadIdx.x >> 6);
    const int l     = threadIdx.x & 63;
    const int hl    = l & 31;
    const int fbase = (l >> 5) * 9;

    float v[9];
    #pragma unroll
    for (int j = 0; j < 9; ++j) {
        const int fj = fbase + j;
        if (fj == 17) {
            float acc = demob[hl];
            #pragma unroll
            for (int d = 0; d < 4; ++d)
                acc = fmaf(statics[b * 4 + d], demoW[hl * 4 + d], acc);
            v[j] = acc;
        } else {
            v[j] = pre[(size_t)b * 576 + fj * 32 + hl];
        }
    }

    float s = 0.0f, ss = 0.0f;
    #pragma unroll
    for (int j = 0; j < 9; ++j) { s += v[j]; ss = fmaf(v[j], v[j], ss); }
    #pragma unroll
    for (int m = 32; m; m >>= 1) { s += __shfl_xor(s, m); ss += __shfl_xor(ss, m); }
    const float mu  = s * (1.0f / 576.0f);
    const float var = ss * (1.0f / 576.0f) - mu * mu;
    const float rs  = frsq(var + 1e-5f);

    float nrm = 0.0f;
    #pragma unroll
    for (int j = 0; j < 9; ++j) {
        const int fj = fbase + j;
        float y = fmaf((v[j] - mu) * rs, lnw[fj * 32 + hl], lnb[fj * 32 + hl]);
        v[j] = y;
        out_ht[(size_t)b * 576 + fj * 32 + hl] = y;
        nrm = fmaf(y, y, nrm);
    }
    #pragma unroll
    for (int m = 32; m; m >>= 1) nrm += __shfl_xor(nrm, m);
    nrm = sqrtf(nrm);

    float dist[8];
    #pragma unroll
    for (int p = 0; p < Pnum; ++p) {
        float d = 0.0f;
        #pragma unroll
        for (int j = 0; j < 9; ++j)
            d = fmaf(v[j], protos[p * 576 + (fbase + j) * 32 + hl], d);
        #pragma unroll
        for (int m = 32; m; m >>= 1) d += __shfl_xor(d, m);
        dist[p] = d / fmaxf(nrm * pnorm[p], 1e-8f);
    }
    if (l == 0) {
        #pragma unroll
        for (int p = 0; p < Pnum; ++p) out_dist[(size_t)b * Pnum + p] = dist[p];
    }

    float q = bq[hl];
    #pragma unroll
    for (int p = 0; p < Pnum; ++p) q = fmaf(dist[p], Wq[hl * 8 + p], q);
    float Sq = q;
    #pragma unroll
    for (int m = 16; m; m >>= 1) Sq += __shfl_xor(Sq, m);

    float sf[9], so[9];
    #pragma unroll
    for (int j = 0; j < 9; ++j) {
        float t = v[j] * q;
        #pragma unroll
        for (int m = 16; m; m >>= 1) t += __shfl_xor(t, m);
        sf[j] = t;
    }
    #pragma unroll
    for (int j = 0; j < 9; ++j) so[j] = __shfl_xor(sf[j], 32);
    const int obase = 9 - fbase;

    float e[8];
    #pragma unroll
    for (int p = 0; p < Pnum; ++p) {
        float a = bk[p] * Sq;
        #pragma unroll
        for (int j = 0; j < 9; ++j) {
            a = fmaf(sf[j], Wk[p * FPn + fbase + j], a);
            a = fmaf(so[j], Wk[p * FPn + obase + j], a);
        }
        e[p] = a;
    }
    float mx = e[0];
    #pragma unroll
    for (int p = 1; p < Pnum; ++p) mx = fmaxf(mx, e[p]);
    float aw[8], den = 0.0f;
    #pragma unroll
    for (int p = 0; p < Pnum; ++p) { aw[p] = __expf(e[p] - mx); den += aw[p]; }
    const float rden = frcp(den);
    #pragma unroll
    for (int p = 0; p < Pnum; ++p) aw[p] *= rden;

    float cc = 0.0f;
    #pragma unroll
    for (int p = 0; p < Pnum; ++p) cc = fmaf(aw[p], bv[p], cc);
    float vb = 0.0f;
    #pragma unroll
    for (int j = 0; j < 9; ++j) {
        float wv = 0.0f;
        #pragma unroll
        for (int p = 0; p < Pnum; ++p) wv = fmaf(aw[p], Wv[p * FPn + fbase + j], wv);
        vb = fmaf(v[j], wv, vb);
    }
    vb += __shfl_xor(vb, 32);
    vb += cc;

    float lg = vb * outW[hl];
    #pragma unroll
    for (int m = 16; m; m >>= 1) lg += __shfl_xor(lg, m);
    lg = fsigmoid(lg + outb[0]);
    if (l == 0) out_logits[b] = lg;
}

extern "C" void kernel_launch(void* const* d_in, const int* in_sizes, int n_in,
                              void* d_out, int out_size, void* d_ws, size_t ws_size,
                              hipStream_t stream) {
    const float* x      = (const float*)d_in[0];
    const float* statics= (const float*)d_in[1];
    const float* Wih    = (const float*)d_in[2];
    const float* Whh    = (const float*)d_in[3];
    const float* bih    = (const float*)d_in[4];
    const float* bhh    = (const float*)d_in[5];
    const float* demoW  = (const float*)d_in[6];
    const float* demob  = (const float*)d_in[7];
    const float* lnw    = (const float*)d_in[8];
    const float* lnb    = (const float*)d_in[9];
    const float* protos = (const float*)d_in[10];
    const float* Wq     = (const float*)d_in[11];
    const float* bq     = (const float*)d_in[12];
    const float* Wk     = (const float*)d_in[13];
    const float* bk     = (const float*)d_in[14];
    const float* Wv     = (const float*)d_in[15];
    const float* bv     = (const float*)d_in[16];
    const float* outW   = (const float*)d_in[17];
    const float* outb   = (const float*)d_in[18];

    // ws layout: pre[B*576] f32 | pnorm[8] f32 | xT[F,T+TPAD,B] bf16
    float* pre   = (float*)d_ws;
    float* pnorm = pre + (size_t)Bsz * FPn * Hdim;
    unsigned short* xT = (unsigned short*)(pnorm + 8);
    const size_t need = ((size_t)Bsz * FPn * Hdim + 8) * 4
                      + (size_t)Fnum * (Tlen + TPAD) * Bsz * 2;
    const bool use_xt = (ws_size >= need);

    prep_pnorm_kernel<<<dim3(1), dim3(256), 0, stream>>>(protos, pnorm);

    if (use_xt) {
        xpose_kernel<<<dim3(Bsz / 64, Tlen), dim3(64), 0, stream>>>(x, xT);
        gru_mfma_kernel<1><<<dim3(Bsz / 64, Fnum), dim3(256), 0, stream>>>(
            x, xT, Wih, Whh, bih, bhh, pre);
    } else {
        gru_mfma_kernel<0><<<dim3(Bsz / 64, Fnum), dim3(256), 0, stream>>>(
            x, xT, Wih, Whh, bih, bhh, pre);
    }

    float* out_logits = (float*)d_out;
    float* out_dist   = out_logits + Bsz;
    float* out_ht     = out_dist + (size_t)Bsz * Pnum;

    post_kernel<<<dim3(Bsz / 4), dim3(256), 0, stream>>>(
        pre, statics, demoW, demob, lnw, lnb, protos, pnorm,
        Wq, bq, Wk, bk, Wv, bv, outW, outb,
        out_logits, out_dist, out_ht);
}

// Round 14
// 839.607 us; speedup vs baseline: 2.2281x; 1.0022x over previous
//
#include <hip/hip_runtime.h>
#include <cmath>

#define Bsz  4096
#define Tlen 512
#define Fnum 17
#define Hdim 32
#define Pnum 8
#define FPn  18
#define G3   96   // 3*Hdim
#define TPAD 8    // extra xT rows so the depth-4 prefetch ring never reads OOB

#define L2E   1.4426950408889634f
#define NL2E (-1.4426950408889634f)
#define TL2E  2.8853900817779268f   // 2*log2(e)

typedef __attribute__((ext_vector_type(8))) short short8v;
typedef __attribute__((ext_vector_type(4))) float float4v;
typedef __attribute__((ext_vector_type(2))) float float2v;

__device__ __forceinline__ float frcp(float x)  { return __builtin_amdgcn_rcpf(x); }
__device__ __forceinline__ float frsq(float x)  { return __builtin_amdgcn_rsqf(x); }
__device__ __forceinline__ float fexp2(float x) { return __builtin_amdgcn_exp2f(x); }
__device__ __forceinline__ float fsigmoid(float x) {
    return frcp(1.0f + fexp2(NL2E * x));
}
// compiler-packed f32 pair ops (backend may select v_pk_* for v2f32 — no inline asm)
__device__ __forceinline__ float2v fma2(float2v a, float2v b, float2v c) {
    return __builtin_elementwise_fma(a, b, c);
}
// RNE float->bf16 bits
__device__ __forceinline__ short bf16b(float x) {
    unsigned u = __float_as_uint(x);
    unsigned r = (u + 0x7FFFu + ((u >> 16) & 1u)) >> 16;
    return (short)r;
}
// packed f32x2 -> bf16x2 (hardware RNE) — proven since R2
__device__ __forceinline__ unsigned cvtpk(float lo, float hi) {
    unsigned r;
    asm("v_cvt_pk_bf16_f32 %0, %1, %2" : "=v"(r) : "v"(lo), "v"(hi));
    return r;
}

// ---------- prep: prototype L2 norms ----------
__global__ void prep_pnorm_kernel(const float* __restrict__ protos, float* __restrict__ pnorm) {
    const int p    = threadIdx.x >> 5;
    const int lane = threadIdx.x & 31;
    float s = 0.0f;
    for (int j = lane; j < FPn * Hdim; j += 32) {
        float v = protos[p * FPn * Hdim + j];
        s = fmaf(v, v, s);
    }
    #pragma unroll
    for (int m = 16; m; m >>= 1) s += __shfl_xor(s, m);
    if (lane == 0) pnorm[p] = sqrtf(s);
}

// ---------- prep: x[B,T,F] -> xT[F,T+TPAD,B] in bf16 ----------
__global__ __launch_bounds__(64)
void xpose_kernel(const float* __restrict__ x, unsigned short* __restrict__ xT) {
    const int b = blockIdx.x * 64 + threadIdx.x;
    const int t = blockIdx.y;
    const float* __restrict__ xp = x + ((size_t)b * Tlen + t) * Fnum;
    #pragma unroll
    for (int ff = 0; ff < Fnum; ++ff)
        xT[(size_t)ff * (Tlen + TPAD) * Bsz + (size_t)t * Bsz + b] = (unsigned short)bf16b(xp[ff]);
}

// ---------- main GRU via chained MFMA (R5-proven math) ------------------------
// Block = ONE wave = (f, 16-b tile); grid = 256 x 17 = 4352 blocks = EXACTLY
// 17 waves/CU (R14: removes the 20-vs-16-wave per-CU imbalance of the 4-wave
// grid, which cost ~18% on the issue-bound critical CU).
// Set1: a_m = Ws@h + C1  (C1 = fp32 bias: NL2E*(bih+bhh) for r,z; TL2E*bhh for n)
// Set2 (chained): e_m = Wx@[x] + a_m  for r,z; e_n = Wx@[x] + TL2E*bih_n for n.
// pi(m,rr) = (m>>1)*32 + 8*(rr>>2) + (m&1)*4 + (rr&3)  [R2-validated]
// Gate combine (R5 exact form): E=e^{2y}, ez=e^{-zhat}:
//   h' = [ez*(E-1) + h*(E+1)] / [(E+1)*(1+ez)]   (per-element rcp)
// Codegen rules learned: fragments built fresh inside the step (R8: hoisted
// partial unions spill 3.3GB); NO setprio (R9: fences 12-MFMA cluster -> spill);
// chained MFMA beats VALU-ih (R12: MFMA issue is free, VALU is the bottleneck);
// raw-bits x-feed + s_sleep stagger (R13, ~-1%).
template<int USE_XT>
__global__ __launch_bounds__(64, 4)
void gru_mfma_kernel(const float* __restrict__ x,
                     const unsigned short* __restrict__ xT,
                     const float* __restrict__ Wih,   // [F,96]
                     const float* __restrict__ Whh,   // [F,96,32]
                     const float* __restrict__ bih,   // [F,96]
                     const float* __restrict__ bhh,   // [F,96]
                     float* __restrict__ pre)         // [B,18,32]
{
    // de-sync co-SIMD waves (distinct blockIdx.x): 0..7 × ~64cyc stagger;
    // timing-only, output-deterministic.
    for (int i = (blockIdx.x & 7); i > 0; --i) __builtin_amdgcn_s_sleep(1);

    const int f  = blockIdx.y;
    const int l  = threadIdx.x;
    const int c  = l & 15, S = l >> 4;
    const int b  = blockIdx.x * 16 + c;

    const float* __restrict__ whh_f = Whh + (size_t)f * G3 * Hdim;
    const float* __restrict__ wih_f = Wih + (size_t)f * G3;
    const float* __restrict__ bih_f = bih + (size_t)f * G3;
    const float* __restrict__ bhh_f = bhh + (size_t)f * G3;

    // ---- one-time per-lane constants ----
    short8v af0, af1, af2, af3, af4, af5;       // Whh fragments (set1)
    short8v g0, g1, g2, g3, g4, g5;             // Wih fragments (set2, k=0 col)
    float4v cin0, cin1, cin2, cin3, cin4, cin5; // fp32 set1 C (bias)
    float4v cb4, cb5;                           // fp32 set2 C for n tiles
    {
        union { short8v s; unsigned u[4]; } au, gu;
        #pragma unroll
        for (int m = 0; m < 6; ++m) {
            const int gate = m >> 1;
            const float sc = (gate < 2) ? NL2E : TL2E;
            const int gA = gate * 32 + 8 * (c >> 2) + (m & 1) * 4 + (c & 3);
            const float* wrow = whh_f + (size_t)gA * Hdim + 8 * S;
            #pragma unroll
            for (int u = 0; u < 4; ++u)
                au.u[u] = cvtpk(wrow[2 * u] * sc, wrow[2 * u + 1] * sc);
            gu.u[0] = (S == 0) ? cvtpk(sc * wih_f[gA], 0.0f) : 0u;
            gu.u[1] = 0u; gu.u[2] = 0u; gu.u[3] = 0u;
            float4v ci;
            #pragma unroll
            for (int q = 0; q < 4; ++q) {
                const int gC = gate * 32 + 8 * S + (m & 1) * 4 + q;
                ci[q] = (gate < 2) ? NL2E * (bhh_f[gC] + bih_f[gC])
                                   : TL2E * bhh_f[gC];
            }
            if (m == 0) { af0 = au.s; g0 = gu.s; cin0 = ci; }
            if (m == 1) { af1 = au.s; g1 = gu.s; cin1 = ci; }
            if (m == 2) { af2 = au.s; g2 = gu.s; cin2 = ci; }
            if (m == 3) { af3 = au.s; g3 = gu.s; cin3 = ci; }
            if (m == 4) { af4 = au.s; g4 = gu.s; cin4 = ci; }
            if (m == 5) { af5 = au.s; g5 = gu.s; cin5 = ci; }
        }
        #pragma unroll
        for (int q = 0; q < 4; ++q) {
            cb4[q] = TL2E * bih_f[64 + 8 * S + q];
            cb5[q] = TL2E * bih_f[64 + 8 * S + 4 + q];
        }
    }
    const unsigned msk = (S == 0) ? 0xFFFFu : 0u;   // only S=0 lanes feed k=0 of B2

    float2v h0 = {0,0}, h1 = {0,0}, h2 = {0,0}, h3 = {0,0};

    // ---- x prefetch ring, depth 4 (phase-relative offsets), raw bf16 bits ----
    const unsigned short* xtp = USE_XT ? (xT + (size_t)f * (Tlen + TPAD) * Bsz + b) : nullptr;
    const float* xp = USE_XT ? nullptr : (x + (size_t)b * Tlen * Fnum + f);
    unsigned x0, x1, x2, x3;
    if (USE_XT) {
        x0 = xtp[0 * Bsz]; x1 = xtp[1 * Bsz]; x2 = xtp[2 * Bsz]; x3 = xtp[3 * Bsz];
    } else {
        x0 = (unsigned short)bf16b(xp[0 * Fnum]);
        x1 = (unsigned short)bf16b(xp[1 * Fnum]);
        x2 = (unsigned short)bf16b(xp[2 * Fnum]);
        x3 = (unsigned short)bf16b(xp[3 * Fnum]);
    }

// ph is relative to the CURRENT xtp/xp (which corresponds to loop time t)
#define LOADX(ph) (USE_XT ? (unsigned)xtp[(size_t)(ph) * Bsz]                        \
                          : ((t + (ph) < Tlen) ? (unsigned)(unsigned short)bf16b(xp[(size_t)(ph) * Fnum]) : 0u))

// R5-proven gate combine, per packed pair (verbatim)
#define GATE_PAIR(hp, ar, az, an, en)                                           \
    {                                                                           \
        const float2v _ar = (ar), _az = (az), _an = (an), _en = (en);           \
        float2v er = {fexp2(_ar.x), fexp2(_ar.y)};                              \
        float2v rp = er + (float2v){1.0f, 1.0f};                                \
        float2v r  = {frcp(rp.x), frcp(rp.y)};                                  \
        float2v ez = {fexp2(_az.x), fexp2(_az.y)};                              \
        float2v y  = fma2(r, _an, _en);                                         \
        float2v E  = {fexp2(y.x), fexp2(y.y)};                                  \
        float2v num = fma2(ez, E, -ez) + fma2(hp, E, hp);                       \
        float2v den = (E + (float2v){1.0f, 1.0f}) * (ez + (float2v){1.0f, 1.0f});\
        float2v rd = {frcp(den.x), frcp(den.y)};                                \
        hp = num * rd;                                                          \
    }

#define LO2(v) ((float2v){(v)[0], (v)[1]})
#define HI2(v) ((float2v){(v)[2], (v)[3]})

#define GRU_STEP(xbits)                                                          \
    {                                                                            \
        union { short8v s; unsigned u[4]; } bu;                                  \
        bu.u[0] = cvtpk(h0.x, h0.y);                                             \
        bu.u[1] = cvtpk(h1.x, h1.y);                                             \
        bu.u[2] = cvtpk(h2.x, h2.y);                                             \
        bu.u[3] = cvtpk(h3.x, h3.y);                                             \
        union { short8v s; unsigned u[4]; } b2;                                  \
        b2.u[0] = (xbits) & msk;                                                 \
        b2.u[1] = 0u; b2.u[2] = 0u; b2.u[3] = 0u;                                \
        const float4v a0 = __builtin_amdgcn_mfma_f32_16x16x32_bf16(af0, bu.s, cin0, 0, 0, 0); \
        const float4v a1 = __builtin_amdgcn_mfma_f32_16x16x32_bf16(af1, bu.s, cin1, 0, 0, 0); \
        const float4v a2 = __builtin_amdgcn_mfma_f32_16x16x32_bf16(af2, bu.s, cin2, 0, 0, 0); \
        const float4v a3 = __builtin_amdgcn_mfma_f32_16x16x32_bf16(af3, bu.s, cin3, 0, 0, 0); \
        const float4v a4 = __builtin_amdgcn_mfma_f32_16x16x32_bf16(af4, bu.s, cin4, 0, 0, 0); \
        const float4v a5 = __builtin_amdgcn_mfma_f32_16x16x32_bf16(af5, bu.s, cin5, 0, 0, 0); \
        const float4v e0 = __builtin_amdgcn_mfma_f32_16x16x32_bf16(g0, b2.s, a0, 0, 0, 0); \
        const float4v e1 = __builtin_amdgcn_mfma_f32_16x16x32_bf16(g1, b2.s, a1, 0, 0, 0); \
        const float4v e2 = __builtin_amdgcn_mfma_f32_16x16x32_bf16(g2, b2.s, a2, 0, 0, 0); \
        const float4v e3 = __builtin_amdgcn_mfma_f32_16x16x32_bf16(g3, b2.s, a3, 0, 0, 0); \
        const float4v e4 = __builtin_amdgcn_mfma_f32_16x16x32_bf16(g4, b2.s, cb4, 0, 0, 0); \
        const float4v e5 = __builtin_amdgcn_mfma_f32_16x16x32_bf16(g5, b2.s, cb5, 0, 0, 0); \
        GATE_PAIR(h0, LO2(e0), LO2(e2), LO2(a4), LO2(e4));                       \
        GATE_PAIR(h1, HI2(e0), HI2(e2), HI2(a4), HI2(e4));                       \
        GATE_PAIR(h2, LO2(e1), LO2(e3), LO2(a5), LO2(e5));                       \
        GATE_PAIR(h3, HI2(e1), HI2(e3), HI2(a5), HI2(e5));                       \
    }

    #pragma unroll 1
    for (int t = 0; t < Tlen; t += 4) {
        GRU_STEP(x0); x0 = LOADX(4);
        GRU_STEP(x1); x1 = LOADX(5);
        GRU_STEP(x2); x2 = LOADX(6);
        GRU_STEP(x3); x3 = LOADX(7);
        if (USE_XT) xtp += 4 * Bsz; else xp += 4 * Fnum;
    }

    float* __restrict__ o = pre + (size_t)b * (FPn * Hdim) + f * Hdim + 8 * S;
    o[0] = h0.x; o[1] = h0.y; o[2] = h1.x; o[3] = h1.y;
    o[4] = h2.x; o[5] = h2.y; o[6] = h3.x; o[7] = h3.y;
#undef GRU_STEP
#undef GATE_PAIR
#undef LOADX
#undef LO2
#undef HI2
}

// ---------- epilogue: 4 waves/block, 1 wave per b.  lane = (h = l&31, f-halfset = l>>5)
__global__ __launch_bounds__(256)
void post_kernel(const float* __restrict__ pre,     // [B,18,32] (f<17 valid)
                 const float* __restrict__ statics, // [B,4]
                 const float* __restrict__ demoW,   // [32,4]
                 const float* __restrict__ demob,   // [32]
                 const float* __restrict__ lnw,     // [18,32]
                 const float* __restrict__ lnb,     // [18,32]
                 const float* __restrict__ protos,  // [8,576]
                 const float* __restrict__ pnorm,   // [8]
                 const float* __restrict__ Wq,      // [32,8]
                 const float* __restrict__ bq,      // [32]
                 const float* __restrict__ Wk,      // [8,18]
                 const float* __restrict__ bk,      // [8]
                 const float* __restrict__ Wv,      // [8,18]
                 const float* __restrict__ bv,      // [8]
                 const float* __restrict__ outW,    // [32]
                 const float* __restrict__ outb,    // [1]
                 float* __restrict__ out_logits,    // [B]
                 float* __restrict__ out_dist,      // [B,8]
                 float* __restrict__ out_ht)        // [B,18,32]
{
    const int b     = blockIdx.x * 4 + (threadIdx.x >> 6);
    const int l     = threadIdx.x & 63;
    const int hl    = l & 31;
    const int fbase = (l >> 5) * 9;

    float v[9];
    #pragma unroll
    for (int j = 0; j < 9; ++j) {
        const int fj = fbase + j;
        if (fj == 17) {
            float acc = demob[hl];
            #pragma unroll
            for (int d = 0; d < 4; ++d)
                acc = fmaf(statics[b * 4 + d], demoW[hl * 4 + d], acc);
            v[j] = acc;
        } else {
            v[j] = pre[(size_t)b * 576 + fj * 32 + hl];
        }
    }

    float s = 0.0f, ss = 0.0f;
    #pragma unroll
    for (int j = 0; j < 9; ++j) { s += v[j]; ss = fmaf(v[j], v[j], ss); }
    #pragma unroll
    for (int m = 32; m; m >>= 1) { s += __shfl_xor(s, m); ss += __shfl_xor(ss, m); }
    const float mu  = s * (1.0f / 576.0f);
    const float var = ss * (1.0f / 576.0f) - mu * mu;
    const float rs  = frsq(var + 1e-5f);

    float nrm = 0.0f;
    #pragma unroll
    for (int j = 0; j < 9; ++j) {
        const int fj = fbase + j;
        float y = fmaf((v[j] - mu) * rs, lnw[fj * 32 + hl], lnb[fj * 32 + hl]);
        v[j] = y;
        out_ht[(size_t)b * 576 + fj * 32 + hl] = y;
        nrm = fmaf(y, y, nrm);
    }
    #pragma unroll
    for (int m = 32; m; m >>= 1) nrm += __shfl_xor(nrm, m);
    nrm = sqrtf(nrm);

    float dist[8];
    #pragma unroll
    for (int p = 0; p < Pnum; ++p) {
        float d = 0.0f;
        #pragma unroll
        for (int j = 0; j < 9; ++j)
            d = fmaf(v[j], protos[p * 576 + (fbase + j) * 32 + hl], d);
        #pragma unroll
        for (int m = 32; m; m >>= 1) d += __shfl_xor(d, m);
        dist[p] = d / fmaxf(nrm * pnorm[p], 1e-8f);
    }
    if (l == 0) {
        #pragma unroll
        for (int p = 0; p < Pnum; ++p) out_dist[(size_t)b * Pnum + p] = dist[p];
    }

    float q = bq[hl];
    #pragma unroll
    for (int p = 0; p < Pnum; ++p) q = fmaf(dist[p], Wq[hl * 8 + p], q);
    float Sq = q;
    #pragma unroll
    for (int m = 16; m; m >>= 1) Sq += __shfl_xor(Sq, m);

    float sf[9], so[9];
    #pragma unroll
    for (int j = 0; j < 9; ++j) {
        float t = v[j] * q;
        #pragma unroll
        for (int m = 16; m; m >>= 1) t += __shfl_xor(t, m);
        sf[j] = t;
    }
    #pragma unroll
    for (int j = 0; j < 9; ++j) so[j] = __shfl_xor(sf[j], 32);
    const int obase = 9 - fbase;

    float e[8];
    #pragma unroll
    for (int p = 0; p < Pnum; ++p) {
        float a = bk[p] * Sq;
        #pragma unroll
        for (int j = 0; j < 9; ++j) {
            a = fmaf(sf[j], Wk[p * FPn + fbase + j], a);
            a = fmaf(so[j], Wk[p * FPn + obase + j], a);
        }
        e[p] = a;
    }
    float mx = e[0];
    #pragma unroll
    for (int p = 1; p < Pnum; ++p) mx = fmaxf(mx, e[p]);
    float aw[8], den = 0.0f;
    #pragma unroll
    for (int p = 0; p < Pnum; ++p) { aw[p] = __expf(e[p] - mx); den += aw[p]; }
    const float rden = frcp(den);
    #pragma unroll
    for (int p = 0; p < Pnum; ++p) aw[p] *= rden;

    float cc = 0.0f;
    #pragma unroll
    for (int p = 0; p < Pnum; ++p) cc = fmaf(aw[p], bv[p], cc);
    float vb = 0.0f;
    #pragma unroll
    for (int j = 0; j < 9; ++j) {
        float wv = 0.0f;
        #pragma unroll
        for (int p = 0; p < Pnum; ++p) wv = fmaf(aw[p], Wv[p * FPn + fbase + j], wv);
        vb = fmaf(v[j], wv, vb);
    }
    vb += __shfl_xor(vb, 32);
    vb += cc;

    float lg = vb * outW[hl];
    #pragma unroll
    for (int m = 16; m; m >>= 1) lg += __shfl_xor(lg, m);
    lg = fsigmoid(lg + outb[0]);
    if (l == 0) out_logits[b] = lg;
}

extern "C" void kernel_launch(void* const* d_in, const int* in_sizes, int n_in,
                              void* d_out, int out_size, void* d_ws, size_t ws_size,
                              hipStream_t stream) {
    const float* x      = (const float*)d_in[0];
    const float* statics= (const float*)d_in[1];
    const float* Wih    = (const float*)d_in[2];
    const float* Whh    = (const float*)d_in[3];
    const float* bih    = (const float*)d_in[4];
    const float* bhh    = (const float*)d_in[5];
    const float* demoW  = (const float*)d_in[6];
    const float* demob  = (const float*)d_in[7];
    const float* lnw    = (const float*)d_in[8];
    const float* lnb    = (const float*)d_in[9];
    const float* protos = (const float*)d_in[10];
    const float* Wq     = (const float*)d_in[11];
    const float* bq     = (const float*)d_in[12];
    const float* Wk     = (const float*)d_in[13];
    const float* bk     = (const float*)d_in[14];
    const float* Wv     = (const float*)d_in[15];
    const float* bv     = (const float*)d_in[16];
    const float* outW   = (const float*)d_in[17];
    const float* outb   = (const float*)d_in[18];

    // ws layout: pre[B*576] f32 | pnorm[8] f32 | xT[F,T+TPAD,B] bf16
    float* pre   = (float*)d_ws;
    float* pnorm = pre + (size_t)Bsz * FPn * Hdim;
    unsigned short* xT = (unsigned short*)(pnorm + 8);
    const size_t need = ((size_t)Bsz * FPn * Hdim + 8) * 4
                      + (size_t)Fnum * (Tlen + TPAD) * Bsz * 2;
    const bool use_xt = (ws_size >= need);

    prep_pnorm_kernel<<<dim3(1), dim3(256), 0, stream>>>(protos, pnorm);

    if (use_xt) {
        xpose_kernel<<<dim3(Bsz / 64, Tlen), dim3(64), 0, stream>>>(x, xT);
        gru_mfma_kernel<1><<<dim3(Bsz / 16, Fnum), dim3(64), 0, stream>>>(
            x, xT, Wih, Whh, bih, bhh, pre);
    } else {
        gru_mfma_kernel<0><<<dim3(Bsz / 16, Fnum), dim3(64), 0, stream>>>(
            x, xT, Wih, Whh, bih, bhh, pre);
    }

    float* out_logits = (float*)d_out;
    float* out_dist   = out_logits + Bsz;
    float* out_ht     = out_dist + (size_t)Bsz * Pnum;

    post_kernel<<<dim3(Bsz / 4), dim3(256), 0, stream>>>(
        pre, statics, demoW, demob, lnw, lnb, protos, pnorm,
        Wq, bq, Wk, bk, Wv, bv, outW, outb,
        out_logits, out_dist, out_ht);
}